// Round 6
// baseline (215465.186 us; speedup 1.0000x reference)
//
#include <hip/hip_runtime.h>
#include <hip/hip_cooperative_groups.h>

namespace cg = cooperative_groups;

constexpr int NB   = 64;     // batch
constexpr int NS   = 256;    // memory length S
constexpr int NT   = 500;    // time steps
constexpr int NMEL = 80;
constexpr int NE   = 512;    // memory dim E
constexpr int NP   = 256;    // prenet dim
constexpr int NA   = 1024;   // attention LSTM hidden
constexpr int ND   = 1024;   // decoder LSTM hidden
constexpr int NAD  = 128;    // attention dim
constexpr int ZC   = 4096;   // 4*hidden
constexpr int KA   = 1792;   // NP + NE + NA
constexpr int KD   = 2560;   // NA + NE + ND
constexpr int NKA  = 11;     // legacy f32 path A k-chunks
constexpr int NKD  = 16;     // legacy f32 path D k-chunks
constexpr int G    = 512;    // legacy grid blocks
constexpr int G2   = 256;    // MODE2 grid blocks (1/CU)

constexpr int SMN  = 5280;   // LDS floats (21.1 KB)

// ---- workspace layout (floats) ----
constexpr int OFF_KEYST = 0;                         // [64][128][256]
constexpr int OFF_FL    = OFF_KEYST + NB * NAD * NS; // [64][128][256]
constexpr int OFF_W2    = OFF_FL + NB * NAD * NS;    // [62][128]
constexpr int OFF_ZA    = OFF_W2 + 62 * NAD;         // atomic mode only
constexpr int OFF_ZD    = OFF_ZA + NB * ZC;          // atomic mode only
constexpr int OFF_HA    = OFF_ZD + NB * ZC;          // zero-block starts here
constexpr int OFF_CA    = OFF_HA + NB * NA;
constexpr int OFF_HD    = OFF_CA + NB * NA;
constexpr int OFF_CD    = OFF_HD + NB * ND;
constexpr int OFF_CTX   = OFF_CD + NB * ND;          // [2][64][512]
constexpr int OFF_WGL   = OFF_CTX + 2 * NB * NE;     // [64][256]
constexpr int OFF_WCU   = OFF_WGL + NB * NS;         // [64][256]
constexpr int OFF_P     = OFF_WCU + NB * NS;         // [2][64][256]
constexpr int OFF_PM1   = OFF_P + 2 * NB * NP;       // [64][256]
constexpr int WS_BASE   = OFF_PM1 + NB * NP;         // 5,136,128 floats
constexpr int ZERO_CNT  = OFF_P - OFF_HA;
// legacy f32-partial extension (MODE 1)
constexpr int OFF_ZAP   = WS_BASE;                    // [11][64][4096]
constexpr int OFF_ZDP   = OFF_ZAP + NKA * NB * ZC;    // [16][64][4096]
constexpr long WS_FULL  = (long)OFF_ZDP + (long)NKD * NB * ZC;
// MODE 2 extension
constexpr long OFF_ZA2  = WS_BASE;                    // [64][4096] f32
constexpr long OFF_ZD2  = OFF_ZA2 + NB * ZC;          // [64][4096] f32
constexpr long OFF_BAR  = OFF_ZD2 + NB * ZC;          // 512 uints barrier state
constexpr long F_END    = OFF_BAR + 512;
// ushort region at (ushort*)(ws + F_END)
constexpr long U_WAT  = 0;                            // [256 n16][56 kb][512] bf16
constexpr long U_WDT  = U_WAT + (long)4096 * KA;      // [256][80][512]
constexpr long U_X16A = U_WDT + (long)4096 * KD;      // [64][1792]
constexpr long U_X16D = U_X16A + (long)NB * KA;       // [64][2560]
constexpr long U_END  = U_X16D + (long)NB * KD;
constexpr long WS_MF_BYTES = F_END * 4 + U_END * 2;   // ~59 MB

constexpr long MEL_BASE   = 0;
constexpr long STOP_BASE  = (long)NB * NT * NMEL;
constexpr long ALIGN_BASE = STOP_BASE + (long)NB * NT;

typedef __attribute__((ext_vector_type(8))) short bf16x8;
typedef __attribute__((ext_vector_type(4))) float f32x4;

struct Params {
  const float *memory, *mel, *pw1, *pw2, *awx, *awh, *ab, *wq, *wm,
              *lconv, *wloc, *vatt, *dwx, *dwh, *db, *projw, *projb, *gatew, *gateb;
  float *out, *ws;
};

__device__ __forceinline__ float sigm(float x) { return 1.f / (1.f + __expf(-x)); }
__device__ __forceinline__ float tanh_t(float x) {
  x = fminf(fmaxf(x, -15.f), 15.f);
  const float a = __expf(2.f * x);
  return (a - 1.f) / (a + 1.f);
}
__device__ __forceinline__ unsigned short f2bf(float x) {  // RNE f32->bf16
  union { float f; unsigned u; } c; c.f = x;
  const unsigned r = c.u + 0x7FFFu + ((c.u >> 16) & 1u);
  return (unsigned short)(r >> 16);
}

// ---- coherent (LLC-routed, no-L2-flush) access helpers ----
// MODE2: cross-block mutable data -> relaxed agent-scope atomics (sc0/sc1 bits,
// no buffer_inv/wbl2). Read-only data keeps plain cached loads -> stays in L2.
template<int MODE>
__device__ __forceinline__ float ldx(const float* p) {
  if constexpr (MODE == 2)
    return __hip_atomic_load(p, __ATOMIC_RELAXED, __HIP_MEMORY_SCOPE_AGENT);
  else return *p;
}
template<int MODE>
__device__ __forceinline__ void stx(float* p, float v) {
  if constexpr (MODE == 2)
    __hip_atomic_store(p, v, __ATOMIC_RELAXED, __HIP_MEMORY_SCOPE_AGENT);
  else *p = v;
}
__device__ __forceinline__ void stu(unsigned short* p, unsigned short v) {
  __hip_atomic_store(p, v, __ATOMIC_RELAXED, __HIP_MEMORY_SCOPE_AGENT);
}
__device__ __forceinline__ bf16x8 ld_bf8_cv(const unsigned short* p) {
  union { unsigned long long q[2]; bf16x8 v; } u;
  u.q[0] = __hip_atomic_load((const unsigned long long*)p,
                             __ATOMIC_RELAXED, __HIP_MEMORY_SCOPE_AGENT);
  u.q[1] = __hip_atomic_load((const unsigned long long*)(p + 4),
                             __ATOMIC_RELAXED, __HIP_MEMORY_SCOPE_AGENT);
  return u.v;
}

// ---- grid barrier: relaxed atomics only (NO agent fences -> L2 stays warm).
// __syncthreads drains each thread's vmem (compiler emits waitcnt before
// s_barrier); cross-visible stores are sc1 write-through, so arrival order
// through the LLC-resident counters is sufficient.
__device__ __forceinline__ void gbar(unsigned* bar, int wg, int tid) {
  __syncthreads();
  if (tid == 0) {
    unsigned* gen  = bar;
    unsigned* root = bar + 32;
    unsigned* leaf = bar + 64 + (wg >> 5) * 32;
    const unsigned g = __hip_atomic_load(gen, __ATOMIC_RELAXED, __HIP_MEMORY_SCOPE_AGENT);
    asm volatile("s_waitcnt vmcnt(0)" ::: "memory");
    const unsigned lo = __hip_atomic_fetch_add(leaf, 1u, __ATOMIC_RELAXED,
                                               __HIP_MEMORY_SCOPE_AGENT);
    if (lo == 31) {
      __hip_atomic_store(leaf, 0u, __ATOMIC_RELAXED, __HIP_MEMORY_SCOPE_AGENT);
      const unsigned ro = __hip_atomic_fetch_add(root, 1u, __ATOMIC_RELAXED,
                                                 __HIP_MEMORY_SCOPE_AGENT);
      if (ro == 7) {
        __hip_atomic_store(root, 0u, __ATOMIC_RELAXED, __HIP_MEMORY_SCOPE_AGENT);
        __hip_atomic_fetch_add(gen, 1u, __ATOMIC_RELAXED, __HIP_MEMORY_SCOPE_AGENT);
      }
    }
    while (__hip_atomic_load(gen, __ATOMIC_RELAXED, __HIP_MEMORY_SCOPE_AGENT) == g)
      __builtin_amdgcn_s_sleep(8);
  }
  __syncthreads();
}

// prenet stage 1 (writes pm1: cross-block)
template<int MODE>
__device__ void do_s1(const Params& p, float* pm1, int tnext, int wl, int tid) {
  const int col = tid;
  for (int i = 0; i < 8; ++i) {
    const int b = wl * 8 + i;
    const float* mrow = p.mel + ((size_t)b * NT + tnext) * NMEL;
    float acc = 0.f;
    for (int k = 0; k < NMEL; ++k) acc += mrow[k] * p.pw1[k * NP + col];
    stx<MODE>(&pm1[b * NP + col], fmaxf(acc, 0.f));
  }
}

// prenet stage 2 (reads pm1 cross; MODE2 writes bf16 xA cross)
template<int MODE>
__device__ void do_s2(const Params& p, const float* pm1, float* pdst,
                      unsigned short* xA, int wl, int tid) {
  const int col = tid;
  for (int i = 0; i < 4; ++i) {
    const int b = wl * 4 + i;
    const float* pr = pm1 + b * NP;
    float acc = 0.f;
    for (int k = 0; k < NP; ++k) acc += ldx<MODE>(&pr[k]) * p.pw2[k * NP + col];
    const float v = fmaxf(acc, 0.f);
    if constexpr (MODE == 2) stu(&xA[(size_t)b * KA + col], f2bf(v));
    else                     pdst[b * NP + col] = v;
  }
}

template<int MODE>
__device__ void pre_a(const Params& p, float* sm, int wg, int tid) {
  float* ws = p.ws;
  const int gid = wg * 256 + tid;
  const int gstr = gridDim.x * 256;
  for (int i = gid; i < ZERO_CNT; i += gstr) (ws + OFF_HA)[i] = 0.f;
  if constexpr (MODE == 0) {
    for (int i = gid; i < NB * ZC; i += gstr) {
      ws[OFF_ZA + i] = p.ab[i & (ZC - 1)];
      ws[OFF_ZD + i] = p.db[i & (ZC - 1)];
    }
  }
  if constexpr (MODE == 2) {
    if (wg == 0) for (int i = tid; i < 512; i += 256) ((unsigned*)(ws + OFF_BAR))[i] = 0;
  }
  // fused conv kernel W2[k2][ad]
  for (int i = gid; i < 62 * NAD; i += gstr) {
    const int k2 = i >> 7, ad = i & 127;
    float acc = 0.f;
    for (int f = 0; f < 32; ++f) acc += p.lconv[k2 * 32 + f] * p.wloc[f * NAD + ad];
    ws[OFF_W2 + i] = acc;
  }
  // keysT[b][ad][s]
  {
    const int nper = (MODE == 2) ? 4 : 8;
    const int schunk = NS / nper;
    const int b = wg / nper, si0 = (wg % nper) * schunk;
    const int sl = tid & 31, adg = tid >> 5;
    const float* wmb = p.wm + adg * 16;
    for (int so = 0; so < schunk; so += 32) {
      const float* mrow = p.memory + (size_t)(b * NS + si0 + so + sl) * NE;
      float acc[16];
#pragma unroll
      for (int j = 0; j < 16; ++j) acc[j] = 0.f;
      for (int k = 0; k < NE; ++k) {
        const float mv = mrow[k];
        const float* wr = wmb + (size_t)k * NAD;
#pragma unroll
        for (int j = 0; j < 16; ++j) acc[j] += mv * wr[j];
      }
#pragma unroll
      for (int j = 0; j < 16; ++j)
        ws[OFF_KEYST + (b * NAD + adg * 16 + j) * NS + si0 + so + sl] = acc[j];
    }
  }
  if constexpr (MODE == 2) {
    unsigned short* u16 = (unsigned short*)(ws + F_END);
    for (long i = gid; i < (long)NB * KA + (long)NB * KD; i += gstr)
      u16[U_X16A + i] = 0;
    // pack bf16 weight fragments: tiles of 32k x 64n
    for (int tile = wg; tile < 3584 + 5120; tile += gridDim.x) {
      const bool iA = tile < 3584;
      const int tt = iA ? tile : tile - 3584;
      const int NKB = iA ? 56 : 80;
      const int nt4 = tt / NKB, kb = tt % NKB;
      const int kx = iA ? 768 : 1536;
      const int r = tid >> 3, cgp = (tid & 7) * 8;
      const int k = kb * 32 + r;
      const float* src = iA
          ? (k < kx ? p.awx + (size_t)k * ZC : p.awh + (size_t)(k - kx) * ZC)
          : (k < kx ? p.dwx + (size_t)k * ZC : p.dwh + (size_t)(k - kx) * ZC);
      const float* sp = src + nt4 * 64 + cgp;
      const float4 v0 = *(const float4*)sp;
      const float4 v1 = *(const float4*)(sp + 4);
      __syncthreads();
      *(float4*)(sm + r * 64 + cgp)     = v0;
      *(float4*)(sm + r * 64 + cgp + 4) = v1;
      __syncthreads();
      const int blk = tid >> 6, l = tid & 63;
      const int n16 = nt4 * 4 + blk;
      bf16x8 pk;
#pragma unroll
      for (int j = 0; j < 8; ++j)
        pk[j] = (short)f2bf(sm[((l >> 4) * 8 + j) * 64 + blk * 16 + (l & 15)]);
      unsigned short* dst = u16 + (iA ? U_WAT : U_WDT)
                          + ((size_t)(n16 * NKB + kb)) * 512 + l * 8;
      *(bf16x8*)dst = pk;
    }
    if (wg >= 192 && wg < 200) do_s1<MODE>(p, ws + OFF_PM1, 0, wg - 192, tid);
  } else {
    if (wg >= 496 && wg < 504) do_s1<MODE>(p, ws + OFF_PM1, 0, wg - 496, tid);
  }
}

template<int MODE>
__device__ void pre_b(const Params& p, int wg, int tid) {
  if (wg >= 128 && wg < 144) {
    unsigned short* xA = (MODE == 2)
        ? (unsigned short*)(p.ws + F_END) + U_X16A : nullptr;
    do_s2<MODE>(p, p.ws + OFF_PM1, p.ws + OFF_P, xA, wg - 128, tid);
  }
}

// location features fl(t)[b][ad][s]; w/w_cum + fb cross-block
template<int MODE>
__device__ void do_fl(const Params& p, float* sm, int b, int tid) {
  float* ws = p.ws;
  float* chunk = sm;
  float* wp0 = sm + 4000;
  float* wp1 = sm + 4320;
  for (int i = tid; i < 288; i += 256) { wp0[i] = 0.f; wp1[i] = 0.f; }
  __syncthreads();
  wp0[15 + tid] = ldx<MODE>(&ws[OFF_WGL + b * NS + tid]);
  wp1[15 + tid] = ldx<MODE>(&ws[OFF_WCU + b * NS + tid]);
  __syncthreads();
  float x0[31], x1[31];
#pragma unroll
  for (int k = 0; k < 31; ++k) { x0[k] = wp0[tid + k]; x1[k] = wp1[tid + k]; }
  const float* kb = ws + OFF_KEYST + (b * NAD) * NS + tid;
  float* fb = ws + OFF_FL + (b * NAD) * NS + tid;
  const float* W2g = ws + OFF_W2;
  for (int ch = 0; ch < 2; ++ch) {
    for (int i = tid; i < 62 * 64; i += 256) {
      const int k2 = i >> 6, adl = i & 63;
      chunk[i] = W2g[k2 * NAD + ch * 64 + adl];
    }
    __syncthreads();
    for (int adl = 0; adl < 64; ++adl) {
      const int ad = ch * 64 + adl;
      float acc = kb[ad * NS];
#pragma unroll
      for (int k = 0; k < 31; ++k)
        acc = fmaf(x0[k], chunk[(2 * k) * 64 + adl],
              fmaf(x1[k], chunk[(2 * k + 1) * 64 + adl], acc));
      stx<MODE>(&fb[ad * NS], acc);
    }
    __syncthreads();
  }
}

template<int MODE>
__device__ void phase1(const Params& p, float* sm, int wg, int tid, int t) {
  float* ws = p.ws;
  if constexpr (MODE == 2) {
    unsigned short* u16 = (unsigned short*)(ws + F_END);
    if (wg < 128) {
      // MFMA GEMMs, full K per wave. A: wg<64 -> z_a(t); D: wg>=64 -> z_d(t-1)
      const bool isA = wg < 64;
      if ((isA && t < NT) || (!isA && t >= 1)) {
        const int g   = isA ? wg : wg - 64;
        const int NKB = isA ? 56 : 80;
        const int Kp  = isA ? KA : KD;
        const unsigned short* wT  = u16 + (isA ? U_WAT : U_WDT);
        const unsigned short* x16 = u16 + (isA ? U_X16A : U_X16D);
        float* zout = ws + (isA ? OFF_ZA2 : OFF_ZD2);
        const int l = tid & 63;
        const int n16 = g * 4 + (tid >> 6);
        const unsigned short* wb = wT + (size_t)n16 * NKB * 512 + l * 8;
        const unsigned short* xb = x16 + (size_t)(l & 15) * Kp + (l >> 4) * 8;
        f32x4 acc[4];
#pragma unroll
        for (int m = 0; m < 4; ++m) acc[m] = f32x4{0.f, 0.f, 0.f, 0.f};
#pragma unroll 2
        for (int ks = 0; ks < NKB; ++ks) {
          const bf16x8 bfr = *(const bf16x8*)(wb + (size_t)ks * 512);  // L2-warm
          const bf16x8 a0 = ld_bf8_cv(xb + ks * 32);
          const bf16x8 a1 = ld_bf8_cv(xb + ks * 32 + (size_t)16 * Kp);
          const bf16x8 a2 = ld_bf8_cv(xb + ks * 32 + (size_t)32 * Kp);
          const bf16x8 a3 = ld_bf8_cv(xb + ks * 32 + (size_t)48 * Kp);
          acc[0] = __builtin_amdgcn_mfma_f32_16x16x32_bf16(a0, bfr, acc[0], 0, 0, 0);
          acc[1] = __builtin_amdgcn_mfma_f32_16x16x32_bf16(a1, bfr, acc[1], 0, 0, 0);
          acc[2] = __builtin_amdgcn_mfma_f32_16x16x32_bf16(a2, bfr, acc[2], 0, 0, 0);
          acc[3] = __builtin_amdgcn_mfma_f32_16x16x32_bf16(a3, bfr, acc[3], 0, 0, 0);
        }
        const int ncol = n16 * 16 + (l & 15);
        const int rb = (l >> 4) * 4;
#pragma unroll
        for (int mb = 0; mb < 4; ++mb)
#pragma unroll
          for (int r = 0; r < 4; ++r)
            stx<2>(&zout[(size_t)(mb * 16 + rb + r) * ZC + ncol], acc[mb][r]);
      }
    } else if (wg < 192) {
      if (t < NT) do_fl<MODE>(p, sm, wg - 128, tid);
    } else if (wg < 200) {
      if (t + 1 < NT) do_s1<MODE>(p, ws + OFF_PM1, t + 1, wg - 192, tid);
    }
    return;
  }
  // ---- legacy f32 paths (MODE 0/1) ----
  if (wg < 176) {
    if (t < NT) {
      const int cb = wg & 7, bs = (wg >> 3) & 1, kci = wg >> 4;
      const int col0 = cb * 512, b0 = bs * 32, k0 = kci * 163;
      const int kc = min(163, KA - k0);
      const float* pcur = ws + OFF_P + (t & 1) * (NB * NP);
      const float* ctxp = ws + OFF_CTX + ((t + 1) & 1) * (NB * NE);
      const float* h_a  = ws + OFF_HA;
      for (int bb = 0; bb < 32; ++bb) {
        const int b = b0 + bb;
        for (int kk = tid; kk < kc; kk += 256) {
          const int k = k0 + kk;
          float v;
          if (k < NP)           v = pcur[b * NP + k];
          else if (k < NP + NE) v = ctxp[b * NE + (k - NP)];
          else                  v = h_a[b * NA + (k - NP - NE)];
          sm[bb * 164 + kk] = v;
        }
      }
      __syncthreads();
      const int bgrp = tid >> 6, cgrp = tid & 63;
      const int c = col0 + cgrp * 8;
      float acc[8][8];
#pragma unroll
      for (int i = 0; i < 8; ++i)
#pragma unroll
        for (int j = 0; j < 8; ++j) acc[i][j] = 0.f;
      const float* sxb = sm + bgrp * 8 * 164;
#pragma unroll 2
      for (int kk = 0; kk < kc; ++kk) {
        const int k = k0 + kk;
        const float* wr = (k < 768) ? (p.awx + (size_t)k * ZC + c)
                                    : (p.awh + (size_t)(k - 768) * ZC + c);
        const float4 w0 = *(const float4*)wr;
        const float4 w1 = *(const float4*)(wr + 4);
#pragma unroll
        for (int i = 0; i < 8; ++i) {
          const float x = sxb[i * 164 + kk];
          acc[i][0] += x * w0.x; acc[i][1] += x * w0.y;
          acc[i][2] += x * w0.z; acc[i][3] += x * w0.w;
          acc[i][4] += x * w1.x; acc[i][5] += x * w1.y;
          acc[i][6] += x * w1.z; acc[i][7] += x * w1.w;
        }
      }
      if constexpr (MODE == 1) {
        float* zap = ws + OFF_ZAP;
#pragma unroll
        for (int i = 0; i < 8; ++i) {
          const int b = b0 + bgrp * 8 + i;
          float* dst = zap + (size_t)(kci * NB + b) * ZC + c;
          *(float4*)dst       = make_float4(acc[i][0], acc[i][1], acc[i][2], acc[i][3]);
          *(float4*)(dst + 4) = make_float4(acc[i][4], acc[i][5], acc[i][6], acc[i][7]);
        }
      } else {
        float* z_a = ws + OFF_ZA;
#pragma unroll
        for (int i = 0; i < 8; ++i) {
          const int b = b0 + bgrp * 8 + i;
#pragma unroll
          for (int j = 0; j < 8; ++j) atomicAdd(&z_a[b * ZC + c + j], acc[i][j]);
        }
      }
      __syncthreads();
    }
  } else if (wg < 432) {
    if (t >= 1) {
      const int lw = wg - 176;
      const int cb = lw & 7, bs = (lw >> 3) & 1, kci = lw >> 4;
      const int col0 = cb * 512, b0 = bs * 32, k0 = kci * 160;
      const int kc = 160;
      const float* ctxp = ws + OFF_CTX + ((t + 1) & 1) * (NB * NE);
      const float* h_a  = ws + OFF_HA;
      const float* h_d  = ws + OFF_HD;
      for (int bb = 0; bb < 32; ++bb) {
        const int b = b0 + bb;
        for (int kk = tid; kk < kc; kk += 256) {
          const int k = k0 + kk;
          float v;
          if (k < NA)           v = h_a[b * NA + k];
          else if (k < NA + NE) v = ctxp[b * NE + (k - NA)];
          else                  v = h_d[b * ND + (k - NA - NE)];
          sm[bb * 161 + kk] = v;
        }
      }
      __syncthreads();
      const int bgrp = tid >> 6, cgrp = tid & 63;
      const int c = col0 + cgrp * 8;
      float acc[8][8];
#pragma unroll
      for (int i = 0; i < 8; ++i)
#pragma unroll
        for (int j = 0; j < 8; ++j) acc[i][j] = 0.f;
      const float* sxb = sm + bgrp * 8 * 161;
#pragma unroll 2
      for (int kk = 0; kk < kc; ++kk) {
        const int k = k0 + kk;
        const float* wr = (k < 1536) ? (p.dwx + (size_t)k * ZC + c)
                                     : (p.dwh + (size_t)(k - 1536) * ZC + c);
        const float4 w0 = *(const float4*)wr;
        const float4 w1 = *(const float4*)(wr + 4);
#pragma unroll
        for (int i = 0; i < 8; ++i) {
          const float x = sxb[i * 161 + kk];
          acc[i][0] += x * w0.x; acc[i][1] += x * w0.y;
          acc[i][2] += x * w0.z; acc[i][3] += x * w0.w;
          acc[i][4] += x * w1.x; acc[i][5] += x * w1.y;
          acc[i][6] += x * w1.z; acc[i][7] += x * w1.w;
        }
      }
      if constexpr (MODE == 1) {
        float* zdp = ws + OFF_ZDP;
#pragma unroll
        for (int i = 0; i < 8; ++i) {
          const int b = b0 + bgrp * 8 + i;
          float* dst = zdp + (size_t)(kci * NB + b) * ZC + c;
          *(float4*)dst       = make_float4(acc[i][0], acc[i][1], acc[i][2], acc[i][3]);
          *(float4*)(dst + 4) = make_float4(acc[i][4], acc[i][5], acc[i][6], acc[i][7]);
        }
      } else {
        float* z_d = ws + OFF_ZD;
#pragma unroll
        for (int i = 0; i < 8; ++i) {
          const int b = b0 + bgrp * 8 + i;
#pragma unroll
          for (int j = 0; j < 8; ++j) atomicAdd(&z_d[b * ZC + c + j], acc[i][j]);
        }
      }
      __syncthreads();
    }
  } else if (wg < 496) {
    if (t < NT) do_fl<MODE>(p, sm, wg - 432, tid);
  } else if (wg < 504) {
    if (t + 1 < NT) do_s1<MODE>(p, ws + OFF_PM1, t + 1, wg - 496, tid);
  }
}

template<int MODE>
__device__ void phase2(const Params& p, float* sm, int wg, int tid, int t) {
  float* ws = p.ws;
  unsigned short* u16 = (MODE == 2) ? (unsigned short*)(ws + F_END) : nullptr;
  if (wg < 64) {
    // attention WG per b
    if (t < NT) {
      const int b = wg;
      float* h_sh = sm;
      float* q_sh = sm + 1024;
      float* red  = sm + 1152;
      float* w_sh = sm + 1408;
      float* c_a  = ws + OFF_CA;   // private to this block across steps
      float* h_a  = ws + OFF_HA;
      unsigned short* xA = (MODE == 2) ? u16 + U_X16A + (size_t)b * KA : nullptr;
      unsigned short* xD = (MODE == 2) ? u16 + U_X16D + (size_t)b * KD : nullptr;
#pragma unroll
      for (int j = 0; j < 4; ++j) {
        const int g = tid + j * 256;
        float zi, zf, zg, zo;
        if constexpr (MODE == 2) {
          const float* za0 = ws + OFF_ZA2 + (size_t)b * ZC;
          zi = p.ab[g]        + ldx<2>(&za0[g]);
          zf = p.ab[1024 + g] + ldx<2>(&za0[1024 + g]);
          zg = p.ab[2048 + g] + ldx<2>(&za0[2048 + g]);
          zo = p.ab[3072 + g] + ldx<2>(&za0[3072 + g]);
        } else if constexpr (MODE == 1) {
          zi = p.ab[g]; zf = p.ab[1024 + g]; zg = p.ab[2048 + g]; zo = p.ab[3072 + g];
          const float* zap = ws + OFF_ZAP + (size_t)b * ZC;
#pragma unroll 1
          for (int kci = 0; kci < NKA; ++kci) {
            const float* zp = zap + (size_t)kci * NB * ZC;
            zi += zp[g]; zf += zp[1024 + g]; zg += zp[2048 + g]; zo += zp[3072 + g];
          }
        } else {
          float* z_a = ws + OFF_ZA;
          zi = z_a[b * ZC + g];
          zf = z_a[b * ZC + 1024 + g];
          zg = z_a[b * ZC + 2048 + g];
          zo = z_a[b * ZC + 3072 + g];
          z_a[b * ZC + g]        = p.ab[g];
          z_a[b * ZC + 1024 + g] = p.ab[1024 + g];
          z_a[b * ZC + 2048 + g] = p.ab[2048 + g];
          z_a[b * ZC + 3072 + g] = p.ab[3072 + g];
        }
        const float cold = c_a[b * NA + g];
        const float iv = sigm(zi), fv = sigm(zf), gv = tanh_t(zg), ov = sigm(zo);
        const float c2 = fv * cold + iv * gv;
        const float h2 = ov * tanh_t(c2);
        c_a[b * NA + g] = c2;
        h_a[b * NA + g] = h2;
        h_sh[g] = h2;
        if constexpr (MODE == 2) {
          stu(&xA[768 + g], f2bf(h2));
          stu(&xD[g],       f2bf(h2));
        }
      }
      __syncthreads();
      // query = h_a(t) @ wq
      {
        const int ad = tid & 127, kh = tid >> 7;
        float acc = 0.f;
        const float* wqp = p.wq + ad;
        for (int k = kh * 512; k < kh * 512 + 512; ++k) acc += h_sh[k] * wqp[(size_t)k * NAD];
        red[tid] = acc;
      }
      __syncthreads();
      if (tid < 128) q_sh[tid] = red[tid] + red[tid + 128];
      __syncthreads();
      // energies
      float ev = 0.f;
      {
        const float* flp = ws + OFF_FL + (b * NAD) * NS + tid;
#pragma unroll 8
        for (int ad = 0; ad < NAD; ++ad)
          ev += tanh_t(q_sh[ad] + ldx<MODE>(&flp[ad * NS])) * p.vatt[ad];
      }
      red[tid] = ev; __syncthreads();
      for (int off = 128; off > 0; off >>= 1) {
        if (tid < off) red[tid] = fmaxf(red[tid], red[tid + off]);
        __syncthreads();
      }
      const float mx = red[0];
      __syncthreads();
      const float ex = __expf(ev - mx);
      red[tid] = ex; __syncthreads();
      for (int off = 128; off > 0; off >>= 1) {
        if (tid < off) red[tid] += red[tid + off];
        __syncthreads();
      }
      const float wv = ex / red[0];
      w_sh[tid] = wv;
      const float wcu_old = ldx<MODE>(&ws[OFF_WCU + b * NS + tid]);
      stx<MODE>(&ws[OFF_WGL + b * NS + tid], wv);
      stx<MODE>(&ws[OFF_WCU + b * NS + tid], wcu_old + wv);
      p.out[ALIGN_BASE + (size_t)b * NT * NS + (size_t)t * NS + tid] = wv;
      __syncthreads();
      // context
      {
        float a0 = 0.f, a1 = 0.f;
        const float* mb = p.memory + (size_t)b * NS * NE;
        for (int ss = 0; ss < NS; ++ss) {
          const float wcur = w_sh[ss];
          a0 += wcur * mb[ss * NE + tid];
          a1 += wcur * mb[ss * NE + tid + 256];
        }
        float* cdst = ws + OFF_CTX + (t & 1) * (NB * NE) + b * NE;
        stx<MODE>(&cdst[tid], a0);
        stx<MODE>(&cdst[tid + 256], a1);
        if constexpr (MODE == 2) {
          stu(&xA[256 + tid],  f2bf(a0));
          stu(&xA[512 + tid],  f2bf(a1));
          stu(&xD[1024 + tid], f2bf(a0));
          stu(&xD[1280 + tid], f2bf(a1));
        }
      }
    }
  } else if (wg < 128) {
    // decoder WG per b
    if (t >= 1) {
      const int b = wg - 64;
      const int tm1 = t - 1;
      float* h_sh = sm;
      float* red  = sm + 1024;
      float* c_d  = ws + OFF_CD;   // private to this block
      float* h_d  = ws + OFF_HD;
      unsigned short* xD = (MODE == 2) ? u16 + U_X16D + (size_t)b * KD : nullptr;
#pragma unroll
      for (int j = 0; j < 4; ++j) {
        const int g = tid + j * 256;
        float zi, zf, zg, zo;
        if constexpr (MODE == 2) {
          const float* zd0 = ws + OFF_ZD2 + (size_t)b * ZC;
          zi = p.db[g]        + ldx<2>(&zd0[g]);
          zf = p.db[1024 + g] + ldx<2>(&zd0[1024 + g]);
          zg = p.db[2048 + g] + ldx<2>(&zd0[2048 + g]);
          zo = p.db[3072 + g] + ldx<2>(&zd0[3072 + g]);
        } else if constexpr (MODE == 1) {
          zi = p.db[g]; zf = p.db[1024 + g]; zg = p.db[2048 + g]; zo = p.db[3072 + g];
          const float* zdp = ws + OFF_ZDP + (size_t)b * ZC;
#pragma unroll 1
          for (int kci = 0; kci < NKD; ++kci) {
            const float* zp = zdp + (size_t)kci * NB * ZC;
            zi += zp[g]; zf += zp[1024 + g]; zg += zp[2048 + g]; zo += zp[3072 + g];
          }
        } else {
          float* z_d = ws + OFF_ZD;
          zi = z_d[b * ZC + g];
          zf = z_d[b * ZC + 1024 + g];
          zg = z_d[b * ZC + 2048 + g];
          zo = z_d[b * ZC + 3072 + g];
          z_d[b * ZC + g]        = p.db[g];
          z_d[b * ZC + 1024 + g] = p.db[1024 + g];
          z_d[b * ZC + 2048 + g] = p.db[2048 + g];
          z_d[b * ZC + 3072 + g] = p.db[3072 + g];
        }
        const float cold = c_d[b * ND + g];
        const float iv = sigm(zi), fv = sigm(zf), gv = tanh_t(zg), ov = sigm(zo);
        const float c2 = fv * cold + iv * gv;
        const float h2 = ov * tanh_t(c2);
        c_d[b * ND + g] = c2;
        h_d[b * ND + g] = h2;
        h_sh[g] = h2;
        if constexpr (MODE == 2) stu(&xD[1536 + g], f2bf(h2));
      }
      __syncthreads();
      float* ctxp = ws + OFF_CTX + (tm1 & 1) * (NB * NE) + b * NE;
      {
        float acc = 0.f;
        for (int k = tid; k < 1536; k += 256) {
          const float v = (k < 1024) ? h_sh[k] : ldx<MODE>(&ctxp[k - 1024]);
          acc += v * p.gatew[k];
        }
        red[tid] = acc;
      }
      __syncthreads();
      for (int off = 128; off > 0; off >>= 1) {
        if (tid < off) red[tid] += red[tid + off];
        __syncthreads();
      }
      if (tid == 0) p.out[STOP_BASE + (size_t)b * NT + tm1] = sigm(red[0] + p.gateb[0]);
      __syncthreads();
      if (tid < 240) {
        const int m = tid % 80, kh = tid / 80;
        float acc = 0.f;
#pragma unroll 4
        for (int k = kh * 512; k < kh * 512 + 512; ++k) {
          const float v = (k < 1024) ? h_sh[k] : ldx<MODE>(&ctxp[k - 1024]);
          acc += v * p.projw[(size_t)k * 80 + m];
        }
        red[kh * 80 + m] = acc;
      }
      __syncthreads();
      if (tid < 80) {
        const float mval = p.projb[tid] + red[tid] + red[80 + tid] + red[160 + tid];
        p.out[MEL_BASE + (size_t)b * NT * NMEL + (size_t)tm1 * NMEL + tid] = mval;
      }
    }
  } else if (wg < 144) {
    if (t + 1 < NT) {
      unsigned short* xA = (MODE == 2) ? u16 + U_X16A : nullptr;
      do_s2<MODE>(p, ws + OFF_PM1, ws + OFF_P + ((t + 1) & 1) * (NB * NP),
                  xA, wg - 128, tid);
    }
  }
}

template<int MODE>
__global__ __launch_bounds__(256, 2) void taco_coop(Params p) {
  cg::grid_group grid = cg::this_grid();
  const int wg  = blockIdx.x;
  const int tid = threadIdx.x;
  __shared__ float sm[SMN];

  pre_a<MODE>(p, sm, wg, tid);
  grid.sync();   // full fence: publishes plain-written init data (incl. wbl2)
  pre_b<MODE>(p, wg, tid);
  grid.sync();
  if constexpr (MODE == 2) {
    unsigned* bar = (unsigned*)(p.ws + OFF_BAR);
    for (int t = 0; t <= NT; ++t) {
      phase1<MODE>(p, sm, wg, tid, t);
      gbar(bar, wg, tid);
      phase2<MODE>(p, sm, wg, tid, t);
      gbar(bar, wg, tid);
    }
  } else {
    for (int t = 0; t <= NT; ++t) {
      phase1<MODE>(p, sm, wg, tid, t);
      grid.sync();
      phase2<MODE>(p, sm, wg, tid, t);
      grid.sync();
    }
  }
}

// ---- non-cooperative fallback (atomic variant) ----
__global__ __launch_bounds__(256, 2) void k_pre_a(Params p) {
  __shared__ float sm[SMN];
  pre_a<0>(p, sm, blockIdx.x, threadIdx.x);
}
__global__ __launch_bounds__(256, 2) void k_pre_b(Params p) { pre_b<0>(p, blockIdx.x, threadIdx.x); }
__global__ __launch_bounds__(256, 2) void k_p1(Params p, int t) {
  __shared__ float sm[SMN];
  phase1<0>(p, sm, blockIdx.x, threadIdx.x, t);
}
__global__ __launch_bounds__(256, 2) void k_p2(Params p, int t) {
  __shared__ float sm[SMN];
  phase2<0>(p, sm, blockIdx.x, threadIdx.x, t);
}

extern "C" void kernel_launch(void* const* d_in, const int* in_sizes, int n_in,
                              void* d_out, int out_size, void* d_ws, size_t ws_size,
                              hipStream_t stream) {
  (void)in_sizes; (void)n_in; (void)out_size;
  Params prm;
  prm.memory = (const float*)d_in[0];
  prm.mel    = (const float*)d_in[1];
  prm.pw1    = (const float*)d_in[2];
  prm.pw2    = (const float*)d_in[3];
  prm.awx    = (const float*)d_in[4];
  prm.awh    = (const float*)d_in[5];
  prm.ab     = (const float*)d_in[6];
  prm.wq     = (const float*)d_in[7];
  prm.wm     = (const float*)d_in[8];
  prm.lconv  = (const float*)d_in[9];
  prm.wloc   = (const float*)d_in[10];
  prm.vatt   = (const float*)d_in[11];
  prm.dwx    = (const float*)d_in[12];
  prm.dwh    = (const float*)d_in[13];
  prm.db     = (const float*)d_in[14];
  prm.projw  = (const float*)d_in[15];
  prm.projb  = (const float*)d_in[16];
  prm.gatew  = (const float*)d_in[17];
  prm.gateb  = (const float*)d_in[18];
  prm.out = (float*)d_out;
  prm.ws  = (float*)d_ws;

  void* args[] = { &prm };
  hipError_t err;
  if (ws_size >= (size_t)WS_MF_BYTES) {
    err = hipLaunchCooperativeKernel((void*)taco_coop<2>, dim3(G2), dim3(256), args, 0, stream);
  } else if (ws_size >= (size_t)WS_FULL * sizeof(float)) {
    err = hipLaunchCooperativeKernel((void*)taco_coop<1>, dim3(G), dim3(256), args, 0, stream);
  } else {
    err = hipLaunchCooperativeKernel((void*)taco_coop<0>, dim3(G), dim3(256), args, 0, stream);
  }
  if (err != hipSuccess) {
    k_pre_a<<<dim3(G), dim3(256), 0, stream>>>(prm);
    k_pre_b<<<dim3(G), dim3(256), 0, stream>>>(prm);
    for (int t = 0; t <= NT; ++t) {
      k_p1<<<dim3(G), dim3(256), 0, stream>>>(prm, t);
      k_p2<<<dim3(G), dim3(256), 0, stream>>>(prm, t);
    }
  }
}

// Round 7
// 171194.434 us; speedup vs baseline: 1.2586x; 1.2586x over previous
//
#include <hip/hip_runtime.h>
#include <hip/hip_cooperative_groups.h>

namespace cg = cooperative_groups;

constexpr int NB   = 64;
constexpr int NS   = 256;
constexpr int NT   = 500;
constexpr int NMEL = 80;
constexpr int NE   = 512;
constexpr int NP   = 256;
constexpr int NA   = 1024;
constexpr int ND   = 1024;
constexpr int NAD  = 128;
constexpr int ZC   = 4096;
constexpr int KA   = 1792;
constexpr int KD   = 2560;
constexpr int NKA  = 11;     // legacy
constexpr int NKD  = 16;     // legacy
constexpr int G    = 512;

constexpr int SMN  = 5280;   // 21.1 KB LDS -> 2 blocks/CU

// ---- legacy layout (MODE 0/1) ----
constexpr int OFF_KEYST = 0;
constexpr int OFF_FL    = OFF_KEYST + NB * NAD * NS;
constexpr int OFF_W2    = OFF_FL + NB * NAD * NS;
constexpr int OFF_ZA    = OFF_W2 + 62 * NAD;
constexpr int OFF_ZD    = OFF_ZA + NB * ZC;
constexpr int OFF_HA    = OFF_ZD + NB * ZC;
constexpr int OFF_CA    = OFF_HA + NB * NA;
constexpr int OFF_HD    = OFF_CA + NB * NA;
constexpr int OFF_CD    = OFF_HD + NB * ND;
constexpr int OFF_CTX   = OFF_CD + NB * ND;
constexpr int OFF_WGL   = OFF_CTX + 2 * NB * NE;
constexpr int OFF_WCU   = OFF_WGL + NB * NS;
constexpr int OFF_P     = OFF_WCU + NB * NS;
constexpr int OFF_PM1   = OFF_P + 2 * NB * NP;
constexpr int WS_BASE   = OFF_PM1 + NB * NP;
constexpr int ZERO_CNT  = OFF_P - OFF_HA;
constexpr int OFF_ZAP   = WS_BASE;
constexpr int OFF_ZDP   = OFF_ZAP + NKA * NB * ZC;
constexpr long WS_FULL  = (long)OFF_ZDP + (long)NKD * NB * ZC;

// ---- MODE2 layout: floats then ushorts ----
constexpr long M2_W2   = 0;                       // [62][128]
constexpr long M2_ZAP  = M2_W2 + 62 * NAD;        // [2][64][4096]
constexpr long M2_ZDP  = M2_ZAP + 2 * NB * ZC;    // [2][64][4096]
constexpr long M2_HA   = M2_ZDP + 2 * NB * ZC;    // zero block start
constexpr long M2_CA   = M2_HA + NB * NA;
constexpr long M2_HD   = M2_CA + NB * NA;
constexpr long M2_CD   = M2_HD + NB * ND;
constexpr long M2_CTX  = M2_CD + NB * ND;         // [2][64][512]
constexpr long M2_WGL  = M2_CTX + 2 * NB * NE;    // [64][256]
constexpr long M2_WCU  = M2_WGL + NB * NS;
constexpr long M2_PM1  = M2_WCU + NB * NS;        // [64][256]
constexpr long M2_ZCNT = M2_PM1 - M2_HA;
constexpr long M2_BAR  = M2_PM1 + NB * NP;        // 1024 uints
constexpr long M2_FEND = M2_BAR + 1024;
// ushorts at (ushort*)(ws + M2_FEND)
constexpr long M2_WAT   = 0;                          // [256 n16][56 kb][512]
constexpr long M2_WDT   = M2_WAT + (long)ZC * KA;     // [256][80][512]
constexpr long M2_X16A  = M2_WDT + (long)ZC * KD;     // [64][1792]
constexpr long M2_X16D  = M2_X16A + (long)NB * KA;    // [64][2560]
constexpr long M2_K16   = M2_X16D + (long)NB * KD;    // [64][128][256]
constexpr long M2_FL16  = M2_K16 + (long)NB * NAD * NS;
constexpr long M2_MEM16 = M2_FL16 + (long)NB * NAD * NS; // [64][256][512]
constexpr long M2_UEND_NM = M2_MEM16;
constexpr long M2_UEND    = M2_MEM16 + (long)NB * NS * NE;
constexpr long M2_BYTES_NM = M2_FEND * 4 + M2_UEND_NM * 2;  // ~50 MB
constexpr long M2_BYTES    = M2_FEND * 4 + M2_UEND * 2;     // ~67 MB

constexpr long MEL_BASE   = 0;
constexpr long STOP_BASE  = (long)NB * NT * NMEL;
constexpr long ALIGN_BASE = STOP_BASE + (long)NB * NT;

typedef __attribute__((ext_vector_type(8))) short bf16x8;
typedef __attribute__((ext_vector_type(4))) float f32x4;

struct Params {
  const float *memory, *mel, *pw1, *pw2, *awx, *awh, *ab, *wq, *wm,
              *lconv, *wloc, *vatt, *dwx, *dwh, *db, *projw, *projb, *gatew, *gateb;
  float *out, *ws;
};

__device__ __forceinline__ float sigm(float x) { return 1.f / (1.f + __expf(-x)); }
__device__ __forceinline__ float tanh_t(float x) {
  x = fminf(fmaxf(x, -15.f), 15.f);
  const float a = __expf(2.f * x);
  return (a - 1.f) / (a + 1.f);
}
__device__ __forceinline__ unsigned short f2bf(float x) {
  union { float f; unsigned u; } c; c.f = x;
  const unsigned r = c.u + 0x7FFFu + ((c.u >> 16) & 1u);
  return (unsigned short)(r >> 16);
}
__device__ __forceinline__ float bf2f(unsigned short v) {
  union { unsigned u; float f; } c; c.u = (unsigned)v << 16;
  return c.f;
}

// ---- fenced grid barrier (r5-proven semantics), 16 leaves x 32 blocks ----
__device__ __forceinline__ void gbar(unsigned* bar, int wg, int tid) {
  __syncthreads();
  if (tid == 0) {
    unsigned* gen  = bar;
    unsigned* root = bar + 32;
    unsigned* leaf = bar + 64 + (wg >> 5) * 32;
    const unsigned g = __hip_atomic_load(gen, __ATOMIC_RELAXED, __HIP_MEMORY_SCOPE_AGENT);
    __threadfence();
    const unsigned lo = __hip_atomic_fetch_add(leaf, 1u, __ATOMIC_ACQ_REL,
                                               __HIP_MEMORY_SCOPE_AGENT);
    if (lo == 31) {
      __hip_atomic_store(leaf, 0u, __ATOMIC_RELAXED, __HIP_MEMORY_SCOPE_AGENT);
      const unsigned ro = __hip_atomic_fetch_add(root, 1u, __ATOMIC_ACQ_REL,
                                                 __HIP_MEMORY_SCOPE_AGENT);
      if (ro == 15) {
        __hip_atomic_store(root, 0u, __ATOMIC_RELAXED, __HIP_MEMORY_SCOPE_AGENT);
        __hip_atomic_fetch_add(gen, 1u, __ATOMIC_ACQ_REL, __HIP_MEMORY_SCOPE_AGENT);
      }
    }
    while (__hip_atomic_load(gen, __ATOMIC_RELAXED, __HIP_MEMORY_SCOPE_AGENT) == g)
      __builtin_amdgcn_s_sleep(16);
    __threadfence();
  }
  __syncthreads();
}

// prenet stage 1
__device__ void do_s1(const Params& p, float* pm1, int tnext, int wl, int tid) {
  const int col = tid;
  for (int i = 0; i < 8; ++i) {
    const int b = wl * 8 + i;
    const float* mrow = p.mel + ((size_t)b * NT + tnext) * NMEL;
    float acc = 0.f;
    for (int k = 0; k < NMEL; ++k) acc += mrow[k] * p.pw1[k * NP + col];
    pm1[b * NP + col] = fmaxf(acc, 0.f);
  }
}

// prenet stage 2
template<int MODE>
__device__ void do_s2(const Params& p, const float* pm1, float* pdst,
                      unsigned short* xA, int wl, int tid) {
  const int col = tid;
  for (int i = 0; i < 4; ++i) {
    const int b = wl * 4 + i;
    const float* pr = pm1 + b * NP;
    float acc = 0.f;
    for (int k = 0; k < NP; ++k) acc += pr[k] * p.pw2[k * NP + col];
    const float v = fmaxf(acc, 0.f);
    if constexpr (MODE == 2) xA[(size_t)b * KA + col] = f2bf(v);
    else                     pdst[b * NP + col] = v;
  }
}

// ================= MODE2 =================
template<bool USEMEM>
__device__ void pre_a2(const Params& p, float* sm, int wg, int tid) {
  float* ws = p.ws;
  unsigned short* u16 = (unsigned short*)(ws + M2_FEND);
  const long gid = wg * 256 + tid;
  const long gstr = (long)G * 256;
  for (long i = gid; i < M2_ZCNT; i += gstr) (ws + M2_HA)[i] = 0.f;
  if (wg == 0) for (int i = tid; i < 1024; i += 256) ((unsigned*)(ws + M2_BAR))[i] = 0;
  for (long i = gid; i < 62 * NAD; i += gstr) {
    const int k2 = (int)(i >> 7), ad = (int)(i & 127);
    float acc = 0.f;
    for (int f = 0; f < 32; ++f) acc += p.lconv[k2 * 32 + f] * p.wloc[f * NAD + ad];
    ws[M2_W2 + i] = acc;
  }
  // keysT bf16 [b][ad][s]: 8 WGs per b
  {
    const int b = wg >> 3, s0 = (wg & 7) * 32;
    const int sl = tid & 31, adg = tid >> 5;
    const float* mrow = p.memory + (size_t)(b * NS + s0 + sl) * NE;
    const float* wmb  = p.wm + adg * 16;
    float acc[16];
#pragma unroll
    for (int j = 0; j < 16; ++j) acc[j] = 0.f;
    for (int k = 0; k < NE; ++k) {
      const float mv = mrow[k];
      const float* wr = wmb + (size_t)k * NAD;
#pragma unroll
      for (int j = 0; j < 16; ++j) acc[j] += mv * wr[j];
    }
#pragma unroll
    for (int j = 0; j < 16; ++j)
      u16[M2_K16 + (size_t)(b * NAD + adg * 16 + j) * NS + s0 + sl] = f2bf(acc[j]);
  }
  // zero x16
  for (long i = gid; i < (long)NB * KA + (long)NB * KD; i += gstr)
    u16[M2_X16A + i] = 0;
  // memory bf16 copy
  if constexpr (USEMEM) {
    for (long i = gid; i < (long)NB * NS * NE; i += gstr)
      u16[M2_MEM16 + i] = f2bf(p.memory[i]);
  }
  // pack bf16 weight fragments: tiles of 32k x 64n
  for (int tile = wg; tile < 3584 + 5120; tile += G) {
    const bool iA = tile < 3584;
    const int tt = iA ? tile : tile - 3584;
    const int NKB = iA ? 56 : 80;
    const int nt4 = tt / NKB, kb = tt % NKB;
    const int kx = iA ? 768 : 1536;
    const int r = tid >> 3, cgp = (tid & 7) * 8;
    const int k = kb * 32 + r;
    const float* src = iA
        ? (k < kx ? p.awx + (size_t)k * ZC : p.awh + (size_t)(k - kx) * ZC)
        : (k < kx ? p.dwx + (size_t)k * ZC : p.dwh + (size_t)(k - kx) * ZC);
    const float* sp = src + nt4 * 64 + cgp;
    const float4 v0 = *(const float4*)sp;
    const float4 v1 = *(const float4*)(sp + 4);
    __syncthreads();
    *(float4*)(sm + r * 64 + cgp)     = v0;
    *(float4*)(sm + r * 64 + cgp + 4) = v1;
    __syncthreads();
    const int blk = tid >> 6, l = tid & 63;
    const int n16 = nt4 * 4 + blk;
    bf16x8 pk;
#pragma unroll
    for (int j = 0; j < 8; ++j)
      pk[j] = (short)f2bf(sm[((l >> 4) * 8 + j) * 64 + blk * 16 + (l & 15)]);
    unsigned short* dst = u16 + (iA ? M2_WAT : M2_WDT)
                        + ((size_t)(n16 * NKB + kb)) * 512 + l * 8;
    *(bf16x8*)dst = pk;
  }
  if (wg >= 320 && wg < 328) do_s1(p, ws + M2_PM1, 0, wg - 320, tid);
}

// location features -> FL16
__device__ void do_fl2(const Params& p, float* sm, int b, int tid) {
  float* ws = p.ws;
  unsigned short* u16 = (unsigned short*)(ws + M2_FEND);
  float* chunk = sm;
  float* wp0 = sm + 4000;
  float* wp1 = sm + 4320;
  for (int i = tid; i < 288; i += 256) { wp0[i] = 0.f; wp1[i] = 0.f; }
  __syncthreads();
  wp0[15 + tid] = ws[M2_WGL + b * NS + tid];
  wp1[15 + tid] = ws[M2_WCU + b * NS + tid];
  __syncthreads();
  float x0[31], x1[31];
#pragma unroll
  for (int k = 0; k < 31; ++k) { x0[k] = wp0[tid + k]; x1[k] = wp1[tid + k]; }
  const unsigned short* kb16 = u16 + M2_K16 + (size_t)(b * NAD) * NS + tid;
  unsigned short* fb16 = u16 + M2_FL16 + (size_t)(b * NAD) * NS + tid;
  const float* W2g = ws + M2_W2;
  for (int ch = 0; ch < 2; ++ch) {
    for (int i = tid; i < 62 * 64; i += 256) {
      const int k2 = i >> 6, adl = i & 63;
      chunk[i] = W2g[k2 * NAD + ch * 64 + adl];
    }
    __syncthreads();
    for (int adl = 0; adl < 64; ++adl) {
      const int ad = ch * 64 + adl;
      float acc = bf2f(kb16[(size_t)ad * NS]);
#pragma unroll
      for (int k = 0; k < 31; ++k)
        acc = fmaf(x0[k], chunk[(2 * k) * 64 + adl],
              fmaf(x1[k], chunk[(2 * k + 1) * 64 + adl], acc));
      fb16[(size_t)ad * NS] = f2bf(acc);
    }
    __syncthreads();
  }
}

__device__ void phase1_2(const Params& p, float* sm, int wg, int tid, int t) {
  float* ws = p.ws;
  unsigned short* u16 = (unsigned short*)(ws + M2_FEND);
  if (wg < 256) {
    // MFMA GEMMs, k-split 2. A: wg<128 -> z_a(t) partials; D: -> z_d(t-1)
    const bool isA = wg < 128;
    if ((isA && t < NT) || (!isA && t >= 1)) {
      const int g   = isA ? wg : wg - 128;
      const int kc  = g & 1, nb4 = g >> 1;            // nb4 0..63
      const int NKB = isA ? 56 : 80;
      const int nks = isA ? 28 : 40;
      const int kb0 = kc * nks;
      const int Kp  = isA ? KA : KD;
      const unsigned short* wT  = u16 + (isA ? M2_WAT : M2_WDT);
      const unsigned short* x16 = u16 + (isA ? M2_X16A : M2_X16D);
      float* zout = ws + (isA ? M2_ZAP : M2_ZDP) + (size_t)kc * NB * ZC;
      const int l = tid & 63;
      const int n16 = nb4 * 4 + (tid >> 6);
      const unsigned short* wb = wT + ((size_t)(n16 * NKB + kb0)) * 512 + l * 8;
      const unsigned short* xb = x16 + (size_t)(l & 15) * Kp + kb0 * 32 + (l >> 4) * 8;
      f32x4 acc[4];
#pragma unroll
      for (int m = 0; m < 4; ++m) acc[m] = f32x4{0.f, 0.f, 0.f, 0.f};
#pragma unroll 4
      for (int ks = 0; ks < nks; ++ks) {
        const bf16x8 bfr = *(const bf16x8*)(wb + (size_t)ks * 512);
        const bf16x8 a0 = *(const bf16x8*)(xb + ks * 32);
        const bf16x8 a1 = *(const bf16x8*)(xb + ks * 32 + (size_t)16 * Kp);
        const bf16x8 a2 = *(const bf16x8*)(xb + ks * 32 + (size_t)32 * Kp);
        const bf16x8 a3 = *(const bf16x8*)(xb + ks * 32 + (size_t)48 * Kp);
        acc[0] = __builtin_amdgcn_mfma_f32_16x16x32_bf16(a0, bfr, acc[0], 0, 0, 0);
        acc[1] = __builtin_amdgcn_mfma_f32_16x16x32_bf16(a1, bfr, acc[1], 0, 0, 0);
        acc[2] = __builtin_amdgcn_mfma_f32_16x16x32_bf16(a2, bfr, acc[2], 0, 0, 0);
        acc[3] = __builtin_amdgcn_mfma_f32_16x16x32_bf16(a3, bfr, acc[3], 0, 0, 0);
      }
      const int ncol = n16 * 16 + (l & 15);
      const int rb = (l >> 4) * 4;
#pragma unroll
      for (int mb = 0; mb < 4; ++mb)
#pragma unroll
        for (int r = 0; r < 4; ++r)
          zout[(size_t)(mb * 16 + rb + r) * ZC + ncol] = acc[mb][r];
    }
  } else if (wg < 320) {
    if (t < NT) do_fl2(p, sm, wg - 256, tid);
  } else if (wg < 328) {
    if (t + 1 < NT) do_s1(p, ws + M2_PM1, t + 1, wg - 320, tid);
  }
}

template<bool USEMEM>
__device__ void phase2_2(const Params& p, float* sm, int wg, int tid, int t) {
  float* ws = p.ws;
  unsigned short* u16 = (unsigned short*)(ws + M2_FEND);
  if (wg < 64) {
    if (t < NT) {
      const int b = wg;
      float* h_sh = sm;
      float* q_sh = sm + 1024;
      float* red  = sm + 1152;
      float* w_sh = sm + 1408;
      float* c_a  = ws + M2_CA;
      float* h_a  = ws + M2_HA;
      unsigned short* xA = u16 + M2_X16A + (size_t)b * KA;
      unsigned short* xD = u16 + M2_X16D + (size_t)b * KD;
      const float* za0 = ws + M2_ZAP + (size_t)b * ZC;
      const float* za1 = za0 + (size_t)NB * ZC;
#pragma unroll
      for (int j = 0; j < 4; ++j) {
        const int g = tid + j * 256;
        const float zi = p.ab[g]        + za0[g]        + za1[g];
        const float zf = p.ab[1024 + g] + za0[1024 + g] + za1[1024 + g];
        const float zg = p.ab[2048 + g] + za0[2048 + g] + za1[2048 + g];
        const float zo = p.ab[3072 + g] + za0[3072 + g] + za1[3072 + g];
        const float cold = c_a[b * NA + g];
        const float iv = sigm(zi), fv = sigm(zf), gv = tanh_t(zg), ov = sigm(zo);
        const float c2 = fv * cold + iv * gv;
        const float h2 = ov * tanh_t(c2);
        c_a[b * NA + g] = c2;
        h_a[b * NA + g] = h2;
        h_sh[g] = h2;
        xA[768 + g] = f2bf(h2);
        xD[g]       = f2bf(h2);
      }
      __syncthreads();
      // query
      {
        const int ad = tid & 127, kh = tid >> 7;
        float acc = 0.f;
        const float* wqp = p.wq + ad;
#pragma unroll 8
        for (int k = kh * 512; k < kh * 512 + 512; ++k) acc += h_sh[k] * wqp[(size_t)k * NAD];
        red[tid] = acc;
      }
      __syncthreads();
      if (tid < 128) q_sh[tid] = red[tid] + red[tid + 128];
      __syncthreads();
      // energies from FL16
      float ev = 0.f;
      {
        const unsigned short* flp = u16 + M2_FL16 + (size_t)(b * NAD) * NS + tid;
#pragma unroll 8
        for (int ad = 0; ad < NAD; ++ad)
          ev += tanh_t(q_sh[ad] + bf2f(flp[(size_t)ad * NS])) * p.vatt[ad];
      }
      red[tid] = ev; __syncthreads();
      for (int off = 128; off > 0; off >>= 1) {
        if (tid < off) red[tid] = fmaxf(red[tid], red[tid + off]);
        __syncthreads();
      }
      const float mx = red[0];
      __syncthreads();
      const float ex = __expf(ev - mx);
      red[tid] = ex; __syncthreads();
      for (int off = 128; off > 0; off >>= 1) {
        if (tid < off) red[tid] += red[tid + off];
        __syncthreads();
      }
      const float wv = ex / red[0];
      w_sh[tid] = wv;
      ws[M2_WGL + b * NS + tid] = wv;
      ws[M2_WCU + b * NS + tid] += wv;
      p.out[ALIGN_BASE + (size_t)b * NT * NS + (size_t)t * NS + tid] = wv;
      __syncthreads();
      // context
      {
        float a0 = 0.f, a1 = 0.f;
        if constexpr (USEMEM) {
          const unsigned short* mb16 = u16 + M2_MEM16 + (size_t)b * NS * NE;
#pragma unroll 8
          for (int ss = 0; ss < NS; ++ss) {
            const float wcur = w_sh[ss];
            a0 += wcur * bf2f(mb16[(size_t)ss * NE + tid]);
            a1 += wcur * bf2f(mb16[(size_t)ss * NE + tid + 256]);
          }
        } else {
          const float* mb = p.memory + (size_t)b * NS * NE;
#pragma unroll 8
          for (int ss = 0; ss < NS; ++ss) {
            const float wcur = w_sh[ss];
            a0 += wcur * mb[(size_t)ss * NE + tid];
            a1 += wcur * mb[(size_t)ss * NE + tid + 256];
          }
        }
        float* cdst = ws + M2_CTX + (t & 1) * (NB * NE) + b * NE;
        cdst[tid] = a0;
        cdst[tid + 256] = a1;
        xA[256 + tid]  = f2bf(a0);
        xA[512 + tid]  = f2bf(a1);
        xD[1024 + tid] = f2bf(a0);
        xD[1280 + tid] = f2bf(a1);
      }
    }
  } else if (wg < 128) {
    if (t >= 1) {
      const int b = wg - 64;
      const int tm1 = t - 1;
      float* h_sh = sm;
      float* red  = sm + 1024;
      float* c_d  = ws + M2_CD;
      float* h_d  = ws + M2_HD;
      unsigned short* xD = u16 + M2_X16D + (size_t)b * KD;
      const float* zd0 = ws + M2_ZDP + (size_t)b * ZC;
      const float* zd1 = zd0 + (size_t)NB * ZC;
#pragma unroll
      for (int j = 0; j < 4; ++j) {
        const int g = tid + j * 256;
        const float zi = p.db[g]        + zd0[g]        + zd1[g];
        const float zf = p.db[1024 + g] + zd0[1024 + g] + zd1[1024 + g];
        const float zg = p.db[2048 + g] + zd0[2048 + g] + zd1[2048 + g];
        const float zo = p.db[3072 + g] + zd0[3072 + g] + zd1[3072 + g];
        const float cold = c_d[b * ND + g];
        const float iv = sigm(zi), fv = sigm(zf), gv = tanh_t(zg), ov = sigm(zo);
        const float c2 = fv * cold + iv * gv;
        const float h2 = ov * tanh_t(c2);
        c_d[b * ND + g] = c2;
        h_d[b * ND + g] = h2;
        h_sh[g] = h2;
        xD[1536 + g] = f2bf(h2);
      }
      __syncthreads();
      const float* ctxp = ws + M2_CTX + (tm1 & 1) * (NB * NE) + b * NE;
      {
        float acc = 0.f;
        for (int k = tid; k < 1536; k += 256) {
          const float v = (k < 1024) ? h_sh[k] : ctxp[k - 1024];
          acc += v * p.gatew[k];
        }
        red[tid] = acc;
      }
      __syncthreads();
      for (int off = 128; off > 0; off >>= 1) {
        if (tid < off) red[tid] += red[tid + off];
        __syncthreads();
      }
      if (tid == 0) p.out[STOP_BASE + (size_t)b * NT + tm1] = sigm(red[0] + p.gateb[0]);
      __syncthreads();
      if (tid < 240) {
        const int m = tid % 80, kh = tid / 80;
        float acc = 0.f;
#pragma unroll 4
        for (int k = kh * 512; k < kh * 512 + 512; ++k) {
          const float v = (k < 1024) ? h_sh[k] : ctxp[k - 1024];
          acc += v * p.projw[(size_t)k * 80 + m];
        }
        red[kh * 80 + m] = acc;
      }
      __syncthreads();
      if (tid < 80) {
        const float mval = p.projb[tid] + red[tid] + red[80 + tid] + red[160 + tid];
        p.out[MEL_BASE + (size_t)b * NT * NMEL + (size_t)tm1 * NMEL + tid] = mval;
      }
    }
  } else if (wg < 144) {
    if (t + 1 < NT)
      do_s2<2>(p, ws + M2_PM1, nullptr, u16 + M2_X16A, wg - 128, tid);
  }
}

template<bool USEMEM>
__global__ __launch_bounds__(256, 2) void taco2(Params p) {
  cg::grid_group grid = cg::this_grid();
  const int wg  = blockIdx.x;
  const int tid = threadIdx.x;
  __shared__ float sm[SMN];

  pre_a2<USEMEM>(p, sm, wg, tid);
  grid.sync();
  if (wg >= 128 && wg < 144)
    do_s2<2>(p, p.ws + M2_PM1, nullptr,
             (unsigned short*)(p.ws + M2_FEND) + M2_X16A, wg - 128, tid);
  grid.sync();
  unsigned* bar = (unsigned*)(p.ws + M2_BAR);
  for (int t = 0; t <= NT; ++t) {
    phase1_2(p, sm, wg, tid, t);
    gbar(bar, wg, tid);
    phase2_2<USEMEM>(p, sm, wg, tid, t);
    gbar(bar, wg, tid);
  }
}

// ================= legacy MODE 0/1 (ws fallback; r3-proven) =================
template<int MODE>
__device__ void pre_a(const Params& p, int wg, int tid) {
  float* ws = p.ws;
  const int gid = wg * 256 + tid;
  for (int i = gid; i < ZERO_CNT; i += G * 256) (ws + OFF_HA)[i] = 0.f;
  if constexpr (MODE == 0) {
    for (int i = gid; i < NB * ZC; i += G * 256) {
      ws[OFF_ZA + i] = p.ab[i & (ZC - 1)];
      ws[OFF_ZD + i] = p.db[i & (ZC - 1)];
    }
  }
  for (int i = gid; i < 62 * NAD; i += G * 256) {
    const int k2 = i >> 7, ad = i & 127;
    float acc = 0.f;
    for (int f = 0; f < 32; ++f) acc += p.lconv[k2 * 32 + f] * p.wloc[f * NAD + ad];
    ws[OFF_W2 + i] = acc;
  }
  {
    const int b = wg >> 3, s0 = (wg & 7) * 32;
    const int sl = tid & 31, adg = tid >> 5;
    const float* mrow = p.memory + (size_t)(b * NS + s0 + sl) * NE;
    const float* wmb  = p.wm + adg * 16;
    float acc[16];
#pragma unroll
    for (int j = 0; j < 16; ++j) acc[j] = 0.f;
    for (int k = 0; k < NE; ++k) {
      const float mv = mrow[k];
      const float* wr = wmb + (size_t)k * NAD;
#pragma unroll
      for (int j = 0; j < 16; ++j) acc[j] += mv * wr[j];
    }
#pragma unroll
    for (int j = 0; j < 16; ++j)
      ws[OFF_KEYST + (b * NAD + adg * 16 + j) * NS + s0 + sl] = acc[j];
  }
  if (wg >= 496 && wg < 504) do_s1(p, ws + OFF_PM1, 0, wg - 496, tid);
}

__device__ void do_fl(const Params& p, float* sm, int b, int tid) {
  float* ws = p.ws;
  float* chunk = sm;
  float* wp0 = sm + 4000;
  float* wp1 = sm + 4320;
  for (int i = tid; i < 288; i += 256) { wp0[i] = 0.f; wp1[i] = 0.f; }
  __syncthreads();
  wp0[15 + tid] = ws[OFF_WGL + b * NS + tid];
  wp1[15 + tid] = ws[OFF_WCU + b * NS + tid];
  __syncthreads();
  float x0[31], x1[31];
#pragma unroll
  for (int k = 0; k < 31; ++k) { x0[k] = wp0[tid + k]; x1[k] = wp1[tid + k]; }
  const float* kb = ws + OFF_KEYST + (b * NAD) * NS + tid;
  float* fb = ws + OFF_FL + (b * NAD) * NS + tid;
  const float* W2g = ws + OFF_W2;
  for (int ch = 0; ch < 2; ++ch) {
    for (int i = tid; i < 62 * 64; i += 256) {
      const int k2 = i >> 6, adl = i & 63;
      chunk[i] = W2g[k2 * NAD + ch * 64 + adl];
    }
    __syncthreads();
    for (int adl = 0; adl < 64; ++adl) {
      const int ad = ch * 64 + adl;
      float acc = kb[ad * NS];
#pragma unroll
      for (int k = 0; k < 31; ++k)
        acc = fmaf(x0[k], chunk[(2 * k) * 64 + adl],
              fmaf(x1[k], chunk[(2 * k + 1) * 64 + adl], acc));
      fb[ad * NS] = acc;
    }
    __syncthreads();
  }
}

template<int MODE>
__device__ void phase1(const Params& p, float* sm, int wg, int tid, int t) {
  float* ws = p.ws;
  if (wg < 176) {
    if (t < NT) {
      const int cb = wg & 7, bs = (wg >> 3) & 1, kci = wg >> 4;
      const int col0 = cb * 512, b0 = bs * 32, k0 = kci * 163;
      const int kc = min(163, KA - k0);
      const float* pcur = ws + OFF_P + (t & 1) * (NB * NP);
      const float* ctxp = ws + OFF_CTX + ((t + 1) & 1) * (NB * NE);
      const float* h_a  = ws + OFF_HA;
      for (int bb = 0; bb < 32; ++bb) {
        const int b = b0 + bb;
        for (int kk = tid; kk < kc; kk += 256) {
          const int k = k0 + kk;
          float v;
          if (k < NP)           v = pcur[b * NP + k];
          else if (k < NP + NE) v = ctxp[b * NE + (k - NP)];
          else                  v = h_a[b * NA + (k - NP - NE)];
          sm[bb * 164 + kk] = v;
        }
      }
      __syncthreads();
      const int bgrp = tid >> 6, cgrp = tid & 63;
      const int c = col0 + cgrp * 8;
      float acc[8][8];
#pragma unroll
      for (int i = 0; i < 8; ++i)
#pragma unroll
        for (int j = 0; j < 8; ++j) acc[i][j] = 0.f;
      const float* sxb = sm + bgrp * 8 * 164;
#pragma unroll 2
      for (int kk = 0; kk < kc; ++kk) {
        const int k = k0 + kk;
        const float* wr = (k < 768) ? (p.awx + (size_t)k * ZC + c)
                                    : (p.awh + (size_t)(k - 768) * ZC + c);
        const float4 w0 = *(const float4*)wr;
        const float4 w1 = *(const float4*)(wr + 4);
#pragma unroll
        for (int i = 0; i < 8; ++i) {
          const float x = sxb[i * 164 + kk];
          acc[i][0] += x * w0.x; acc[i][1] += x * w0.y;
          acc[i][2] += x * w0.z; acc[i][3] += x * w0.w;
          acc[i][4] += x * w1.x; acc[i][5] += x * w1.y;
          acc[i][6] += x * w1.z; acc[i][7] += x * w1.w;
        }
      }
      if constexpr (MODE == 1) {
        float* zap = ws + OFF_ZAP;
#pragma unroll
        for (int i = 0; i < 8; ++i) {
          const int b = b0 + bgrp * 8 + i;
          float* dst = zap + (size_t)(kci * NB + b) * ZC + c;
          *(float4*)dst       = make_float4(acc[i][0], acc[i][1], acc[i][2], acc[i][3]);
          *(float4*)(dst + 4) = make_float4(acc[i][4], acc[i][5], acc[i][6], acc[i][7]);
        }
      } else {
        float* z_a = ws + OFF_ZA;
#pragma unroll
        for (int i = 0; i < 8; ++i) {
          const int b = b0 + bgrp * 8 + i;
#pragma unroll
          for (int j = 0; j < 8; ++j) atomicAdd(&z_a[b * ZC + c + j], acc[i][j]);
        }
      }
      __syncthreads();
    }
  } else if (wg < 432) {
    if (t >= 1) {
      const int lw = wg - 176;
      const int cb = lw & 7, bs = (lw >> 3) & 1, kci = lw >> 4;
      const int col0 = cb * 512, b0 = bs * 32, k0 = kci * 160;
      const int kc = 160;
      const float* ctxp = ws + OFF_CTX + ((t + 1) & 1) * (NB * NE);
      const float* h_a  = ws + OFF_HA;
      const float* h_d  = ws + OFF_HD;
      for (int bb = 0; bb < 32; ++bb) {
        const int b = b0 + bb;
        for (int kk = tid; kk < kc; kk += 256) {
          const int k = k0 + kk;
          float v;
          if (k < NA)           v = h_a[b * NA + k];
          else if (k < NA + NE) v = ctxp[b * NE + (k - NA)];
          else                  v = h_d[b * ND + (k - NA - NE)];
          sm[bb * 161 + kk] = v;
        }
      }
      __syncthreads();
      const int bgrp = tid >> 6, cgrp = tid & 63;
      const int c = col0 + cgrp * 8;
      float acc[8][8];
#pragma unroll
      for (int i = 0; i < 8; ++i)
#pragma unroll
        for (int j = 0; j < 8; ++j) acc[i][j] = 0.f;
      const float* sxb = sm + bgrp * 8 * 161;
#pragma unroll 2
      for (int kk = 0; kk < kc; ++kk) {
        const int k = k0 + kk;
        const float* wr = (k < 1536) ? (p.dwx + (size_t)k * ZC + c)
                                     : (p.dwh + (size_t)(k - 1536) * ZC + c);
        const float4 w0 = *(const float4*)wr;
        const float4 w1 = *(const float4*)(wr + 4);
#pragma unroll
        for (int i = 0; i < 8; ++i) {
          const float x = sxb[i * 161 + kk];
          acc[i][0] += x * w0.x; acc[i][1] += x * w0.y;
          acc[i][2] += x * w0.z; acc[i][3] += x * w0.w;
          acc[i][4] += x * w1.x; acc[i][5] += x * w1.y;
          acc[i][6] += x * w1.z; acc[i][7] += x * w1.w;
        }
      }
      if constexpr (MODE == 1) {
        float* zdp = ws + OFF_ZDP;
#pragma unroll
        for (int i = 0; i < 8; ++i) {
          const int b = b0 + bgrp * 8 + i;
          float* dst = zdp + (size_t)(kci * NB + b) * ZC + c;
          *(float4*)dst       = make_float4(acc[i][0], acc[i][1], acc[i][2], acc[i][3]);
          *(float4*)(dst + 4) = make_float4(acc[i][4], acc[i][5], acc[i][6], acc[i][7]);
        }
      } else {
        float* z_d = ws + OFF_ZD;
#pragma unroll
        for (int i = 0; i < 8; ++i) {
          const int b = b0 + bgrp * 8 + i;
#pragma unroll
          for (int j = 0; j < 8; ++j) atomicAdd(&z_d[b * ZC + c + j], acc[i][j]);
        }
      }
      __syncthreads();
    }
  } else if (wg < 496) {
    if (t < NT) do_fl(p, sm, wg - 432, tid);
  } else if (wg < 504) {
    if (t + 1 < NT) do_s1(p, ws + OFF_PM1, t + 1, wg - 496, tid);
  }
}

template<int MODE>
__device__ void phase2(const Params& p, float* sm, int wg, int tid, int t) {
  float* ws = p.ws;
  if (wg < 64) {
    if (t < NT) {
      const int b = wg;
      float* h_sh = sm;
      float* q_sh = sm + 1024;
      float* red  = sm + 1152;
      float* w_sh = sm + 1408;
      float* c_a  = ws + OFF_CA;
      float* h_a  = ws + OFF_HA;
#pragma unroll
      for (int j = 0; j < 4; ++j) {
        const int g = tid + j * 256;
        float zi, zf, zg, zo;
        if constexpr (MODE == 1) {
          zi = p.ab[g]; zf = p.ab[1024 + g]; zg = p.ab[2048 + g]; zo = p.ab[3072 + g];
          const float* zap = ws + OFF_ZAP + (size_t)b * ZC;
#pragma unroll 1
          for (int kci = 0; kci < NKA; ++kci) {
            const float* zp = zap + (size_t)kci * NB * ZC;
            zi += zp[g]; zf += zp[1024 + g]; zg += zp[2048 + g]; zo += zp[3072 + g];
          }
        } else {
          float* z_a = ws + OFF_ZA;
          zi = z_a[b * ZC + g];
          zf = z_a[b * ZC + 1024 + g];
          zg = z_a[b * ZC + 2048 + g];
          zo = z_a[b * ZC + 3072 + g];
          z_a[b * ZC + g]        = p.ab[g];
          z_a[b * ZC + 1024 + g] = p.ab[1024 + g];
          z_a[b * ZC + 2048 + g] = p.ab[2048 + g];
          z_a[b * ZC + 3072 + g] = p.ab[3072 + g];
        }
        const float cold = c_a[b * NA + g];
        const float iv = sigm(zi), fv = sigm(zf), gv = tanh_t(zg), ov = sigm(zo);
        const float c2 = fv * cold + iv * gv;
        const float h2 = ov * tanh_t(c2);
        c_a[b * NA + g] = c2;
        h_a[b * NA + g] = h2;
        h_sh[g] = h2;
      }
      __syncthreads();
      {
        const int ad = tid & 127, kh = tid >> 7;
        float acc = 0.f;
        const float* wqp = p.wq + ad;
        for (int k = kh * 512; k < kh * 512 + 512; ++k) acc += h_sh[k] * wqp[(size_t)k * NAD];
        red[tid] = acc;
      }
      __syncthreads();
      if (tid < 128) q_sh[tid] = red[tid] + red[tid + 128];
      __syncthreads();
      float ev = 0.f;
      {
        const float* flp = ws + OFF_FL + (b * NAD) * NS + tid;
        for (int ad = 0; ad < NAD; ++ad)
          ev += tanh_t(q_sh[ad] + flp[ad * NS]) * p.vatt[ad];
      }
      red[tid] = ev; __syncthreads();
      for (int off = 128; off > 0; off >>= 1) {
        if (tid < off) red[tid] = fmaxf(red[tid], red[tid + off]);
        __syncthreads();
      }
      const float mx = red[0];
      __syncthreads();
      const float ex = __expf(ev - mx);
      red[tid] = ex; __syncthreads();
      for (int off = 128; off > 0; off >>= 1) {
        if (tid < off) red[tid] += red[tid + off];
        __syncthreads();
      }
      const float wv = ex / red[0];
      w_sh[tid] = wv;
      ws[OFF_WGL + b * NS + tid] = wv;
      ws[OFF_WCU + b * NS + tid] += wv;
      p.out[ALIGN_BASE + (size_t)b * NT * NS + (size_t)t * NS + tid] = wv;
      __syncthreads();
      {
        float a0 = 0.f, a1 = 0.f;
        const float* mb = p.memory + (size_t)b * NS * NE;
        for (int ss = 0; ss < NS; ++ss) {
          const float wcur = w_sh[ss];
          a0 += wcur * mb[ss * NE + tid];
          a1 += wcur * mb[ss * NE + tid + 256];
        }
        float* cdst = ws + OFF_CTX + (t & 1) * (NB * NE) + b * NE;
        cdst[tid] = a0;
        cdst[tid + 256] = a1;
      }
    }
  } else if (wg < 128) {
    if (t >= 1) {
      const int b = wg - 64;
      const int tm1 = t - 1;
      float* h_sh = sm;
      float* red  = sm + 1024;
      float* c_d  = ws + OFF_CD;
      float* h_d  = ws + OFF_HD;
#pragma unroll
      for (int j = 0; j < 4; ++j) {
        const int g = tid + j * 256;
        float zi, zf, zg, zo;
        if constexpr (MODE == 1) {
          zi = p.db[g]; zf = p.db[1024 + g]; zg = p.db[2048 + g]; zo = p.db[3072 + g];
          const float* zdp = ws + OFF_ZDP + (size_t)b * ZC;
#pragma unroll 1
          for (int kci = 0; kci < NKD; ++kci) {
            const float* zp = zdp + (size_t)kci * NB * ZC;
            zi += zp[g]; zf += zp[1024 + g]; zg += zp[2048 + g]; zo += zp[3072 + g];
          }
        } else {
          float* z_d = ws + OFF_ZD;
          zi = z_d[b * ZC + g];
          zf = z_d[b * ZC + 1024 + g];
          zg = z_d[b * ZC + 2048 + g];
          zo = z_d[b * ZC + 3072 + g];
          z_d[b * ZC + g]        = p.db[g];
          z_d[b * ZC + 1024 + g] = p.db[1024 + g];
          z_d[b * ZC + 2048 + g] = p.db[2048 + g];
          z_d[b * ZC + 3072 + g] = p.db[3072 + g];
        }
        const float cold = c_d[b * ND + g];
        const float iv = sigm(zi), fv = sigm(zf), gv = tanh_t(zg), ov = sigm(zo);
        const float c2 = fv * cold + iv * gv;
        const float h2 = ov * tanh_t(c2);
        c_d[b * ND + g] = c2;
        h_d[b * ND + g] = h2;
        h_sh[g] = h2;
      }
      __syncthreads();
      const float* ctxp = ws + OFF_CTX + (tm1 & 1) * (NB * NE) + b * NE;
      {
        float acc = 0.f;
        for (int k = tid; k < 1536; k += 256) {
          const float v = (k < 1024) ? h_sh[k] : ctxp[k - 1024];
          acc += v * p.gatew[k];
        }
        red[tid] = acc;
      }
      __syncthreads();
      for (int off = 128; off > 0; off >>= 1) {
        if (tid < off) red[tid] += red[tid + off];
        __syncthreads();
      }
      if (tid == 0) p.out[STOP_BASE + (size_t)b * NT + tm1] = sigm(red[0] + p.gateb[0]);
      __syncthreads();
      if (tid < 240) {
        const int m = tid % 80, kh = tid / 80;
        float acc = 0.f;
        for (int k = kh * 512; k < kh * 512 + 512; ++k) {
          const float v = (k < 1024) ? h_sh[k] : ctxp[k - 1024];
          acc += v * p.projw[(size_t)k * 80 + m];
        }
        red[kh * 80 + m] = acc;
      }
      __syncthreads();
      if (tid < 80) {
        const float mval = p.projb[tid] + red[tid] + red[80 + tid] + red[160 + tid];
        p.out[MEL_BASE + (size_t)b * NT * NMEL + (size_t)tm1 * NMEL + tid] = mval;
      }
    }
  } else if (wg < 144) {
    if (t + 1 < NT)
      do_s2<MODE>(p, ws + OFF_PM1, ws + OFF_P + ((t + 1) & 1) * (NB * NP),
                  nullptr, wg - 128, tid);
  }
}

template<int MODE>
__global__ __launch_bounds__(256, 2) void taco_coop(Params p) {
  cg::grid_group grid = cg::this_grid();
  const int wg  = blockIdx.x;
  const int tid = threadIdx.x;
  __shared__ float sm[SMN];
  pre_a<MODE>(p, wg, tid);
  grid.sync();
  if (wg >= 128 && wg < 144)
    do_s2<MODE>(p, p.ws + OFF_PM1, p.ws + OFF_P, nullptr, wg - 128, tid);
  grid.sync();
  for (int t = 0; t <= NT; ++t) {
    phase1<MODE>(p, sm, wg, tid, t);
    grid.sync();
    phase2<MODE>(p, sm, wg, tid, t);
    grid.sync();
  }
}

__global__ __launch_bounds__(256, 2) void k_pre_a(Params p) { pre_a<0>(p, blockIdx.x, threadIdx.x); }
__global__ __launch_bounds__(256, 2) void k_pre_b(Params p) {
  if (blockIdx.x >= 128 && blockIdx.x < 144)
    do_s2<0>(p, p.ws + OFF_PM1, p.ws + OFF_P, nullptr, blockIdx.x - 128, threadIdx.x);
}
__global__ __launch_bounds__(256, 2) void k_p1(Params p, int t) {
  __shared__ float sm[SMN];
  phase1<0>(p, sm, blockIdx.x, threadIdx.x, t);
}
__global__ __launch_bounds__(256, 2) void k_p2(Params p, int t) {
  __shared__ float sm[SMN];
  phase2<0>(p, sm, blockIdx.x, threadIdx.x, t);
}

extern "C" void kernel_launch(void* const* d_in, const int* in_sizes, int n_in,
                              void* d_out, int out_size, void* d_ws, size_t ws_size,
                              hipStream_t stream) {
  (void)in_sizes; (void)n_in; (void)out_size;
  Params prm;
  prm.memory = (const float*)d_in[0];
  prm.mel    = (const float*)d_in[1];
  prm.pw1    = (const float*)d_in[2];
  prm.pw2    = (const float*)d_in[3];
  prm.awx    = (const float*)d_in[4];
  prm.awh    = (const float*)d_in[5];
  prm.ab     = (const float*)d_in[6];
  prm.wq     = (const float*)d_in[7];
  prm.wm     = (const float*)d_in[8];
  prm.lconv  = (const float*)d_in[9];
  prm.wloc   = (const float*)d_in[10];
  prm.vatt   = (const float*)d_in[11];
  prm.dwx    = (const float*)d_in[12];
  prm.dwh    = (const float*)d_in[13];
  prm.db     = (const float*)d_in[14];
  prm.projw  = (const float*)d_in[15];
  prm.projb  = (const float*)d_in[16];
  prm.gatew  = (const float*)d_in[17];
  prm.gateb  = (const float*)d_in[18];
  prm.out = (float*)d_out;
  prm.ws  = (float*)d_ws;

  void* args[] = { &prm };
  hipError_t err;
  if (ws_size >= (size_t)M2_BYTES) {
    err = hipLaunchCooperativeKernel((void*)taco2<true>, dim3(G), dim3(256), args, 0, stream);
  } else if (ws_size >= (size_t)M2_BYTES_NM) {
    err = hipLaunchCooperativeKernel((void*)taco2<false>, dim3(G), dim3(256), args, 0, stream);
  } else if (ws_size >= (size_t)WS_FULL * sizeof(float)) {
    err = hipLaunchCooperativeKernel((void*)taco_coop<1>, dim3(G), dim3(256), args, 0, stream);
  } else {
    err = hipLaunchCooperativeKernel((void*)taco_coop<0>, dim3(G), dim3(256), args, 0, stream);
  }
  if (err != hipSuccess) {
    k_pre_a<<<dim3(G), dim3(256), 0, stream>>>(prm);
    k_pre_b<<<dim3(G), dim3(256), 0, stream>>>(prm);
    for (int t = 0; t <= NT; ++t) {
      k_p1<<<dim3(G), dim3(256), 0, stream>>>(prm, t);
      k_p2<<<dim3(G), dim3(256), 0, stream>>>(prm, t);
    }
  }
}

// Round 8
// 97253.326 us; speedup vs baseline: 2.2155x; 1.7603x over previous
//
#include <hip/hip_runtime.h>
#include <hip/hip_cooperative_groups.h>

namespace cg = cooperative_groups;

constexpr int NB   = 64;
constexpr int NS   = 256;
constexpr int NT   = 500;
constexpr int NMEL = 80;
constexpr int NE   = 512;
constexpr int NP   = 256;
constexpr int NA   = 1024;
constexpr int ND   = 1024;
constexpr int NAD  = 128;
constexpr int ZC   = 4096;
constexpr int KA   = 1792;
constexpr int KD   = 2560;
constexpr int NKA  = 11;     // legacy
constexpr int NKD  = 16;     // legacy
constexpr int G    = 512;

constexpr int SMN  = 5280;   // legacy static LDS floats

// ---- legacy layout (MODE 0/1) ----
constexpr int OFF_KEYST = 0;
constexpr int OFF_FL    = OFF_KEYST + NB * NAD * NS;
constexpr int OFF_W2    = OFF_FL + NB * NAD * NS;
constexpr int OFF_ZA    = OFF_W2 + 62 * NAD;
constexpr int OFF_ZD    = OFF_ZA + NB * ZC;
constexpr int OFF_HA    = OFF_ZD + NB * ZC;
constexpr int OFF_CA    = OFF_HA + NB * NA;
constexpr int OFF_HD    = OFF_CA + NB * NA;
constexpr int OFF_CD    = OFF_HD + NB * ND;
constexpr int OFF_CTX   = OFF_CD + NB * ND;
constexpr int OFF_WGL   = OFF_CTX + 2 * NB * NE;
constexpr int OFF_WCU   = OFF_WGL + NB * NS;
constexpr int OFF_P     = OFF_WCU + NB * NS;
constexpr int OFF_PM1   = OFF_P + 2 * NB * NP;
constexpr int WS_BASE   = OFF_PM1 + NB * NP;
constexpr int ZERO_CNT  = OFF_P - OFF_HA;
constexpr int OFF_ZAP   = WS_BASE;
constexpr int OFF_ZDP   = OFF_ZAP + NKA * NB * ZC;
constexpr long WS_FULL  = (long)OFF_ZDP + (long)NKD * NB * ZC;

// ---- MODE2 layout (r7 fallback) ----
constexpr long M2_W2   = 0;
constexpr long M2_ZAP  = M2_W2 + 62 * NAD;
constexpr long M2_ZDP  = M2_ZAP + 2 * NB * ZC;
constexpr long M2_HA   = M2_ZDP + 2 * NB * ZC;
constexpr long M2_CA   = M2_HA + NB * NA;
constexpr long M2_HD   = M2_CA + NB * NA;
constexpr long M2_CD   = M2_HD + NB * ND;
constexpr long M2_CTX  = M2_CD + NB * ND;
constexpr long M2_WGL  = M2_CTX + 2 * NB * NE;
constexpr long M2_WCU  = M2_WGL + NB * NS;
constexpr long M2_PM1  = M2_WCU + NB * NS;
constexpr long M2_ZCNT = M2_PM1 - M2_HA;
constexpr long M2_BAR  = M2_PM1 + NB * NP;
constexpr long M2_FEND = M2_BAR + 1024;
constexpr long M2_WAT   = 0;
constexpr long M2_WDT   = M2_WAT + (long)ZC * KA;
constexpr long M2_X16A  = M2_WDT + (long)ZC * KD;
constexpr long M2_X16D  = M2_X16A + (long)NB * KA;
constexpr long M2_K16   = M2_X16D + (long)NB * KD;
constexpr long M2_FL16  = M2_K16 + (long)NB * NAD * NS;
constexpr long M2_MEM16 = M2_FL16 + (long)NB * NAD * NS;
constexpr long M2_UEND_NM = M2_MEM16;
constexpr long M2_UEND    = M2_MEM16 + (long)NB * NS * NE;
constexpr long M2_BYTES_NM = M2_FEND * 4 + M2_UEND_NM * 2;
constexpr long M2_BYTES    = M2_FEND * 4 + M2_UEND * 2;

// ---- MODE3 layout: LDS-resident weights ----
constexpr int G3 = 256, T3 = 512;
constexpr long M3_W2   = 0;                         // [62][128]
constexpr long M3_ZA   = M3_W2 + 62 * NAD;          // [64][4096]
constexpr long M3_ZD   = M3_ZA + NB * ZC;           // [64][4096]
constexpr long M3_CTX  = M3_ZD + NB * ZC;           // [2][64][512]
constexpr long M3_WGL  = M3_CTX + 2 * NB * NE;      // [64][256]
constexpr long M3_WCU  = M3_WGL + NB * NS;
constexpr long M3_PM1  = M3_WCU + NB * NS;          // [64][256]
constexpr long M3_BAR  = M3_PM1 + NB * NP;          // 1024 uints
constexpr long M3_FEND = M3_BAR + 1024;
// ushorts at (ushort*)(ws + M3_FEND)
constexpr long M3_WAT  = 0;                          // [256][56][512]
constexpr long M3_WDT  = M3_WAT + (long)ZC * KA;     // [256][80][512]
constexpr long M3_X16A = M3_WDT + (long)ZC * KD;     // [64][1792]
constexpr long M3_X16D = M3_X16A + (long)NB * KA;    // [64][2560]
constexpr long M3_K16  = M3_X16D + (long)NB * KD;    // [64][128][256]
constexpr long M3_FL16 = M3_K16 + (long)NB * NAD * NS;
constexpr long M3_WQ16 = M3_FL16 + (long)NB * NAD * NS; // [1024][128]
constexpr long M3_MEMT = M3_WQ16 + (long)NA * NAD;   // [64][512][256] transposed
constexpr long M3_UEND = M3_MEMT + (long)NB * NE * NS;
constexpr long M3_BYTES = M3_FEND * 4 + M3_UEND * 2; // ~64.2 MB
constexpr int  DYN_LDS  = 159744;                    // 57344 + 81920 + 20480

constexpr long MEL_BASE   = 0;
constexpr long STOP_BASE  = (long)NB * NT * NMEL;
constexpr long ALIGN_BASE = STOP_BASE + (long)NB * NT;

typedef __attribute__((ext_vector_type(8))) short bf16x8;
typedef __attribute__((ext_vector_type(4))) float f32x4;

struct Params {
  const float *memory, *mel, *pw1, *pw2, *awx, *awh, *ab, *wq, *wm,
              *lconv, *wloc, *vatt, *dwx, *dwh, *db, *projw, *projb, *gatew, *gateb;
  float *out, *ws;
};

__device__ __forceinline__ float sigm(float x) { return 1.f / (1.f + __expf(-x)); }
__device__ __forceinline__ float tanh_t(float x) {
  x = fminf(fmaxf(x, -15.f), 15.f);
  const float a = __expf(2.f * x);
  return (a - 1.f) / (a + 1.f);
}
__device__ __forceinline__ unsigned short f2bf(float x) {
  union { float f; unsigned u; } c; c.f = x;
  const unsigned r = c.u + 0x7FFFu + ((c.u >> 16) & 1u);
  return (unsigned short)(r >> 16);
}
__device__ __forceinline__ float bf2f(unsigned short v) {
  union { unsigned u; float f; } c; c.u = (unsigned)v << 16;
  return c.f;
}

// ---- fenced grid barrier, 32-block leaves (512-grid legacy) ----
__device__ __forceinline__ void gbar(unsigned* bar, int wg, int tid) {
  __syncthreads();
  if (tid == 0) {
    unsigned* gen  = bar;
    unsigned* root = bar + 32;
    unsigned* leaf = bar + 64 + (wg >> 5) * 32;
    const unsigned g = __hip_atomic_load(gen, __ATOMIC_RELAXED, __HIP_MEMORY_SCOPE_AGENT);
    __threadfence();
    const unsigned lo = __hip_atomic_fetch_add(leaf, 1u, __ATOMIC_ACQ_REL,
                                               __HIP_MEMORY_SCOPE_AGENT);
    if (lo == 31) {
      __hip_atomic_store(leaf, 0u, __ATOMIC_RELAXED, __HIP_MEMORY_SCOPE_AGENT);
      const unsigned ro = __hip_atomic_fetch_add(root, 1u, __ATOMIC_ACQ_REL,
                                                 __HIP_MEMORY_SCOPE_AGENT);
      if (ro == 15) {
        __hip_atomic_store(root, 0u, __ATOMIC_RELAXED, __HIP_MEMORY_SCOPE_AGENT);
        __hip_atomic_fetch_add(gen, 1u, __ATOMIC_ACQ_REL, __HIP_MEMORY_SCOPE_AGENT);
      }
    }
    while (__hip_atomic_load(gen, __ATOMIC_RELAXED, __HIP_MEMORY_SCOPE_AGENT) == g)
      __builtin_amdgcn_s_sleep(16);
    __threadfence();
  }
  __syncthreads();
}

// ---- fenced grid barrier, 16 leaves x 16 blocks (MODE3, 256-grid) ----
__device__ __forceinline__ void gbar3(unsigned* bar, int wg, int tid) {
  __syncthreads();
  if (tid == 0) {
    unsigned* gen  = bar;
    unsigned* root = bar + 32;
    unsigned* leaf = bar + 64 + (wg >> 4) * 32;
    const unsigned g = __hip_atomic_load(gen, __ATOMIC_RELAXED, __HIP_MEMORY_SCOPE_AGENT);
    __threadfence();
    const unsigned lo = __hip_atomic_fetch_add(leaf, 1u, __ATOMIC_ACQ_REL,
                                               __HIP_MEMORY_SCOPE_AGENT);
    if (lo == 15) {
      __hip_atomic_store(leaf, 0u, __ATOMIC_RELAXED, __HIP_MEMORY_SCOPE_AGENT);
      const unsigned ro = __hip_atomic_fetch_add(root, 1u, __ATOMIC_ACQ_REL,
                                                 __HIP_MEMORY_SCOPE_AGENT);
      if (ro == 15) {
        __hip_atomic_store(root, 0u, __ATOMIC_RELAXED, __HIP_MEMORY_SCOPE_AGENT);
        __hip_atomic_fetch_add(gen, 1u, __ATOMIC_ACQ_REL, __HIP_MEMORY_SCOPE_AGENT);
      }
    }
    while (__hip_atomic_load(gen, __ATOMIC_RELAXED, __HIP_MEMORY_SCOPE_AGENT) == g)
      __builtin_amdgcn_s_sleep(8);
    __threadfence();
  }
  __syncthreads();
}

// prenet stage 1 (call with tid<256)
__device__ void do_s1(const Params& p, float* pm1, int tnext, int wl, int tid) {
  const int col = tid;
  for (int i = 0; i < 8; ++i) {
    const int b = wl * 8 + i;
    const float* mrow = p.mel + ((size_t)b * NT + tnext) * NMEL;
    float acc = 0.f;
    for (int k = 0; k < NMEL; ++k) acc += mrow[k] * p.pw1[k * NP + col];
    pm1[b * NP + col] = fmaxf(acc, 0.f);
  }
}

// prenet stage 2 (call with tid<256)
template<int MODE>
__device__ void do_s2(const Params& p, const float* pm1, float* pdst,
                      unsigned short* xA, int wl, int tid) {
  const int col = tid;
  for (int i = 0; i < 4; ++i) {
    const int b = wl * 4 + i;
    const float* pr = pm1 + b * NP;
    float acc = 0.f;
    for (int k = 0; k < NP; ++k) acc += pr[k] * p.pw2[k * NP + col];
    const float v = fmaxf(acc, 0.f);
    if constexpr (MODE >= 2) xA[(size_t)b * KA + col] = f2bf(v);
    else                     pdst[b * NP + col] = v;
  }
}

// ======================= MODE3 =======================
__device__ void do_fl3(const Params& p, float* scr, unsigned short* u16, int wg, int tid) {
  float* ws = p.ws;
  float* chunk = scr;              // 3968 f
  float* wp = scr + 3968;          // [2][2][288]
  const int hf = tid >> 8, ts = tid & 255;
  const int b = (wg - 144) * 2 + hf;
  float* wp0 = wp + hf * 576;
  float* wp1 = wp0 + 288;
  for (int i = ts; i < 288; i += 256) { wp0[i] = 0.f; wp1[i] = 0.f; }
  __syncthreads();
  wp0[15 + ts] = ws[M3_WGL + b * NS + ts];
  wp1[15 + ts] = ws[M3_WCU + b * NS + ts];
  __syncthreads();
  float x0[31], x1[31];
#pragma unroll
  for (int k = 0; k < 31; ++k) { x0[k] = wp0[ts + k]; x1[k] = wp1[ts + k]; }
  const unsigned short* kb16 = u16 + M3_K16 + (size_t)(b * NAD) * NS + ts;
  unsigned short* fb16 = u16 + M3_FL16 + (size_t)(b * NAD) * NS + ts;
  const float* W2g = ws + M3_W2;
  for (int ch = 0; ch < 2; ++ch) {
    for (int i = tid; i < 62 * 64; i += T3) {
      const int k2 = i >> 6, adl = i & 63;
      chunk[i] = W2g[k2 * NAD + ch * 64 + adl];
    }
    __syncthreads();
    for (int adl = 0; adl < 64; ++adl) {
      const int ad = ch * 64 + adl;
      float acc = bf2f(kb16[(size_t)ad * NS]);
#pragma unroll
      for (int k = 0; k < 31; ++k)
        acc = fmaf(x0[k], chunk[(2 * k) * 64 + adl],
              fmaf(x1[k], chunk[(2 * k + 1) * 64 + adl], acc));
      fb16[(size_t)ad * NS] = f2bf(acc);
    }
    __syncthreads();
  }
}

__device__ void attn3(const Params& p, float* scr, unsigned short* u16,
                      int b, int tid, int t, float& c0, float& c1) {
  if (t >= NT) return;
  float* ws = p.ws;
  float* h_sh = scr;
  float* red  = scr + 1024;
  float* q_sh = scr + 1536;
  float* w_sh = scr + 1664;
  unsigned short* xA = u16 + M3_X16A + (size_t)b * KA;
  unsigned short* xD = u16 + M3_X16D + (size_t)b * KD;
  const float* za = ws + M3_ZA + (size_t)b * ZC;
#pragma unroll
  for (int j = 0; j < 2; ++j) {
    const int g = tid + j * 512;
    const float zi = p.ab[g] + za[g];
    const float zf = p.ab[1024 + g] + za[1024 + g];
    const float zg = p.ab[2048 + g] + za[2048 + g];
    const float zo = p.ab[3072 + g] + za[3072 + g];
    float& cc = j ? c1 : c0;
    const float iv = sigm(zi), fv = sigm(zf), gv = tanh_t(zg), ov = sigm(zo);
    const float cn = fv * cc + iv * gv;
    const float h2 = ov * tanh_t(cn);
    cc = cn;
    h_sh[g] = h2;
    xA[768 + g] = f2bf(h2);
    xD[g]       = f2bf(h2);
  }
  __syncthreads();
  // query: ad 128 x 4-way ksplit (bf16 wq)
  {
    const int ad = tid & 127, kh = tid >> 7;
    const unsigned short* wqp = u16 + M3_WQ16 + ad;
    float acc = 0.f;
#pragma unroll 16
    for (int k = kh * 256; k < kh * 256 + 256; ++k) acc += h_sh[k] * bf2f(wqp[(size_t)k * NAD]);
    red[tid] = acc;
  }
  __syncthreads();
  if (tid < 128) q_sh[tid] = red[tid] + red[tid + 128] + red[tid + 256] + red[tid + 384];
  __syncthreads();
  // energies: s 256 x 2-way ad-split
  float evp = 0.f;
  {
    const int s = tid & 255, hf = tid >> 8;
    const unsigned short* flp = u16 + M3_FL16 + (size_t)(b * NAD + hf * 64) * NS + s;
    const float* qs = q_sh + hf * 64;
    const float* va = p.vatt + hf * 64;
#pragma unroll 8
    for (int ad = 0; ad < 64; ++ad)
      evp += tanh_t(qs[ad] + bf2f(flp[(size_t)ad * NS])) * va[ad];
  }
  red[tid] = evp;
  __syncthreads();
  float evs = 0.f;
  if (tid < 256) evs = red[tid] + red[tid + 256];
  __syncthreads();
  if (tid < 256) red[tid] = evs;
  __syncthreads();
  for (int off = 128; off > 0; off >>= 1) {
    if (tid < off) red[tid] = fmaxf(red[tid], red[tid + off]);
    __syncthreads();
  }
  const float mx = red[0];
  __syncthreads();
  const float ex = (tid < 256) ? __expf(evs - mx) : 0.f;
  red[tid] = ex;
  __syncthreads();
  for (int off = 128; off > 0; off >>= 1) {
    if (tid < off) red[tid] += red[tid + off];
    __syncthreads();
  }
  const float sden = red[0];
  if (tid < 256) {
    const float wv = ex / sden;
    w_sh[tid] = wv;
    ws[M3_WGL + b * NS + tid] = wv;
    ws[M3_WCU + b * NS + tid] += wv;
    p.out[ALIGN_BASE + (size_t)b * NT * NS + (size_t)t * NS + tid] = wv;
  }
  __syncthreads();
  // context from transposed bf16 memory: e = tid, contiguous s-run
  {
    const int e = tid;
    const unsigned short* mrow = u16 + M3_MEMT + ((size_t)b * NE + e) * NS;
    float a0 = 0.f;
#pragma unroll 4
    for (int sc = 0; sc < 32; ++sc) {
      const bf16x8 v = *(const bf16x8*)(mrow + sc * 8);
#pragma unroll
      for (int j = 0; j < 8; ++j) a0 += w_sh[sc * 8 + j] * bf2f((unsigned short)v[j]);
    }
    float* cdst = ws + M3_CTX + (t & 1) * (NB * NE) + b * NE;
    cdst[e] = a0;
    xA[256 + e]  = f2bf(a0);
    xD[1024 + e] = f2bf(a0);
  }
}

__device__ void dec3(const Params& p, float* scr, unsigned short* u16,
                     int b, int tid, int t, float& c0, float& c1) {
  if (t < 1) return;
  const int tm1 = t - 1;
  float* ws = p.ws;
  float* h_sh = scr;
  float* red  = scr + 1024;
  unsigned short* xD = u16 + M3_X16D + (size_t)b * KD;
  const float* zd = ws + M3_ZD + (size_t)b * ZC;
#pragma unroll
  for (int j = 0; j < 2; ++j) {
    const int g = tid + j * 512;
    const float zi = p.db[g] + zd[g];
    const float zf = p.db[1024 + g] + zd[1024 + g];
    const float zg = p.db[2048 + g] + zd[2048 + g];
    const float zo = p.db[3072 + g] + zd[3072 + g];
    float& cc = j ? c1 : c0;
    const float iv = sigm(zi), fv = sigm(zf), gv = tanh_t(zg), ov = sigm(zo);
    const float cn = fv * cc + iv * gv;
    const float h2 = ov * tanh_t(cn);
    cc = cn;
    h_sh[g] = h2;
    xD[1536 + g] = f2bf(h2);
  }
  __syncthreads();
  const float* ctxf = ws + M3_CTX + (tm1 & 1) * (NB * NE) + b * NE;
  // stop gate
  red[tid] = h_sh[tid] * p.gatew[tid] + h_sh[tid + 512] * p.gatew[tid + 512]
           + ctxf[tid] * p.gatew[tid + 1024];
  __syncthreads();
  for (int off = 256; off > 0; off >>= 1) {
    if (tid < off) red[tid] += red[tid + off];
    __syncthreads();
  }
  if (tid == 0) p.out[STOP_BASE + (size_t)b * NT + tm1] = sigm(red[0] + p.gateb[0]);
  __syncthreads();
  // mel projection: 80 m x 6-way ksplit
  if (tid < 480) {
    const int m = tid % 80, kh = tid / 80;
    float acc = 0.f;
#pragma unroll 8
    for (int k = kh * 256; k < kh * 256 + 256; ++k) {
      const float v = (k < 1024) ? h_sh[k] : ctxf[k - 1024];
      acc += v * p.projw[(size_t)k * 80 + m];
    }
    red[kh * 80 + m] = acc;
  }
  __syncthreads();
  if (tid < 80) {
    float mval = p.projb[tid];
#pragma unroll
    for (int kh = 0; kh < 6; ++kh) mval += red[kh * 80 + tid];
    p.out[MEL_BASE + (size_t)b * NT * NMEL + (size_t)tm1 * NMEL + tid] = mval;
  }
}

__global__ __launch_bounds__(512, 1) void taco3(Params p) {
  cg::grid_group grid = cg::this_grid();
  const int wg = blockIdx.x, tid = threadIdx.x;
  extern __shared__ char dynsm[];
  unsigned short* wA_l = (unsigned short*)dynsm;              // 57344 B
  unsigned short* wD_l = (unsigned short*)(dynsm + 57344);    // 81920 B
  float* scr = (float*)(dynsm + 139264);                      // 20480 B scratch
  float* ws = p.ws;
  unsigned short* u16 = (unsigned short*)(ws + M3_FEND);

  // ---------------- pre-phase A ----------------
  {
    const long gid = (long)wg * T3 + tid, gstr = (long)G3 * T3;
    for (long i = gid; i < 98304; i += gstr) ws[M3_CTX + i] = 0.f;  // ctx+w+wcum
    if (wg == 0) for (int i = tid; i < 1024; i += T3) ((unsigned*)(ws + M3_BAR))[i] = 0;
    for (long i = gid; i < 62 * NAD; i += gstr) {
      const int k2 = (int)(i >> 7), ad = (int)(i & 127);
      float a = 0.f;
      for (int f = 0; f < 32; ++f) a += p.lconv[k2 * 32 + f] * p.wloc[f * NAD + ad];
      ws[M3_W2 + i] = a;
    }
    for (long i = gid; i < (long)NB * KA + (long)NB * KD; i += gstr) u16[M3_X16A + i] = 0;
    for (long i = gid; i < (long)NA * NAD; i += gstr) u16[M3_WQ16 + i] = f2bf(p.wq[i]);
    for (long i = gid; i < (long)NB * NE * NS; i += gstr) {
      const int s = (int)(i & 255);
      const long be = i >> 8;
      const int e = (int)(be & 511), b = (int)(be >> 9);
      u16[M3_MEMT + i] = f2bf(p.memory[((size_t)b * NS + s) * NE + e]);
    }
    // keysT bf16: 4 WGs per b, 64-s chunk, 16 ad-groups of 8
    {
      const int b = wg >> 2, s0 = (wg & 3) * 64;
      const int sl = tid & 31, adg = tid >> 5;  // 0..15
      const float* wmb = p.wm + adg * 8;
      for (int so = 0; so < 64; so += 32) {
        const float* mrow = p.memory + (size_t)(b * NS + s0 + so + sl) * NE;
        float acc[8];
#pragma unroll
        for (int j = 0; j < 8; ++j) acc[j] = 0.f;
        for (int k = 0; k < NE; ++k) {
          const float mv = mrow[k];
          const float* wr = wmb + (size_t)k * NAD;
#pragma unroll
          for (int j = 0; j < 8; ++j) acc[j] += mv * wr[j];
        }
#pragma unroll
        for (int j = 0; j < 8; ++j)
          u16[M3_K16 + (size_t)(b * NAD + adg * 8 + j) * NS + s0 + so + sl] = f2bf(acc[j]);
      }
    }
    // pack bf16 weight fragments -> global WAT/WDT (tiles of 32k x 64n)
    for (int tile = wg; tile < 3584 + 5120; tile += G3) {
      const bool iA = tile < 3584;
      const int tt = iA ? tile : tile - 3584;
      const int NKB = iA ? 56 : 80;
      const int nt4 = tt / NKB, kb = tt % NKB;
      const int kx = iA ? 768 : 1536;
      float4 v0{}, v1{};
      if (tid < 256) {
        const int r = tid >> 3, cgp = (tid & 7) * 8;
        const int k = kb * 32 + r;
        const float* src = iA
            ? (k < kx ? p.awx + (size_t)k * ZC : p.awh + (size_t)(k - kx) * ZC)
            : (k < kx ? p.dwx + (size_t)k * ZC : p.dwh + (size_t)(k - kx) * ZC);
        const float* sp = src + nt4 * 64 + cgp;
        v0 = *(const float4*)sp;
        v1 = *(const float4*)(sp + 4);
      }
      __syncthreads();
      if (tid < 256) {
        const int r = tid >> 3, cgp = (tid & 7) * 8;
        *(float4*)(scr + r * 64 + cgp)     = v0;
        *(float4*)(scr + r * 64 + cgp + 4) = v1;
      }
      __syncthreads();
      if (tid < 256) {
        const int blk = tid >> 6, l = tid & 63;
        const int n16 = nt4 * 4 + blk;
        bf16x8 pk;
#pragma unroll
        for (int j = 0; j < 8; ++j)
          pk[j] = (short)f2bf(scr[((l >> 4) * 8 + j) * 64 + blk * 16 + (l & 15)]);
        unsigned short* dst = u16 + (iA ? M3_WAT : M3_WDT)
                            + ((size_t)(n16 * NKB + kb)) * 512 + l * 8;
        *(bf16x8*)dst = pk;
      }
      __syncthreads();
    }
    if (wg >= 176 && wg < 184 && tid < 256) do_s1(p, ws + M3_PM1, 0, wg - 176, tid);
  }
  grid.sync();
  // ---------------- pre-phase B: LDS-stage weights; s2(0) ----------------
  {
    const float4* srcA = (const float4*)(u16 + M3_WAT + (size_t)wg * 56 * 512);
    float4* dA = (float4*)wA_l;
    for (int i = tid; i < 3584; i += T3) dA[i] = srcA[i];
    const float4* srcD = (const float4*)(u16 + M3_WDT + (size_t)wg * 80 * 512);
    float4* dD = (float4*)wD_l;
    for (int i = tid; i < 5120; i += T3) dD[i] = srcD[i];
    if (wg >= 128 && wg < 144 && tid < 256)
      do_s2<3>(p, ws + M3_PM1, nullptr, u16 + M3_X16A, wg - 128, tid);
  }
  grid.sync();

  float c0 = 0.f, c1 = 0.f;   // recurrent cell state in registers (attn/dec roles)
  unsigned* bar = (unsigned*)(ws + M3_BAR);
  for (int t = 0; t <= NT; ++t) {
    // ========== phase 1 ==========
    {
      const int wid = tid >> 6, l = tid & 63;
      if (wid < 4) {
        if (t < NT) {  // A-GEMM: wave = M-frag, n16 = wg
          const unsigned short* xb = u16 + M3_X16A
              + (size_t)(wid * 16 + (l & 15)) * KA + (l >> 4) * 8;
          f32x4 acc{0.f, 0.f, 0.f, 0.f};
#pragma unroll 8
          for (int ks = 0; ks < 56; ++ks) {
            const bf16x8 bfr = *(const bf16x8*)(wA_l + ks * 512 + l * 8);
            const bf16x8 a   = *(const bf16x8*)(xb + ks * 32);
            acc = __builtin_amdgcn_mfma_f32_16x16x32_bf16(a, bfr, acc, 0, 0, 0);
          }
          const int ncol = wg * 16 + (l & 15), rb = (l >> 4) * 4;
          float* z = ws + M3_ZA;
#pragma unroll
          for (int r = 0; r < 4; ++r) z[(size_t)(wid * 16 + rb + r) * ZC + ncol] = acc[r];
        }
      } else {
        if (t >= 1) {  // D-GEMM
          const int mb = wid - 4;
          const unsigned short* xb = u16 + M3_X16D
              + (size_t)(mb * 16 + (l & 15)) * KD + (l >> 4) * 8;
          f32x4 acc{0.f, 0.f, 0.f, 0.f};
#pragma unroll 8
          for (int ks = 0; ks < 80; ++ks) {
            const bf16x8 bfr = *(const bf16x8*)(wD_l + ks * 512 + l * 8);
            const bf16x8 a   = *(const bf16x8*)(xb + ks * 32);
            acc = __builtin_amdgcn_mfma_f32_16x16x32_bf16(a, bfr, acc, 0, 0, 0);
          }
          const int ncol = wg * 16 + (l & 15), rb = (l >> 4) * 4;
          float* z = ws + M3_ZD;
#pragma unroll
          for (int r = 0; r < 4; ++r) z[(size_t)(mb * 16 + rb + r) * ZC + ncol] = acc[r];
        }
      }
      if (wg >= 144 && wg < 176) {
        if (t < NT) do_fl3(p, scr, u16, wg, tid);
      } else if (wg >= 176 && wg < 184) {
        if (t + 1 < NT && tid < 256) do_s1(p, ws + M3_PM1, t + 1, wg - 176, tid);
      }
    }
    gbar3(bar, wg, tid);
    // ========== phase 2 ==========
    if (wg < 64)       attn3(p, scr, u16, wg, tid, t, c0, c1);
    else if (wg < 128) dec3(p, scr, u16, wg - 64, tid, t, c0, c1);
    else if (wg < 144) {
      if (t + 1 < NT && tid < 256)
        do_s2<3>(p, ws + M3_PM1, nullptr, u16 + M3_X16A, wg - 128, tid);
    }
    gbar3(bar, wg, tid);
  }
}

// ======================= MODE2 (r7 fallback) =======================
template<bool USEMEM>
__device__ void pre_a2(const Params& p, float* sm, int wg, int tid) {
  float* ws = p.ws;
  unsigned short* u16 = (unsigned short*)(ws + M2_FEND);
  const long gid = wg * 256 + tid;
  const long gstr = (long)G * 256;
  for (long i = gid; i < M2_ZCNT; i += gstr) (ws + M2_HA)[i] = 0.f;
  if (wg == 0) for (int i = tid; i < 1024; i += 256) ((unsigned*)(ws + M2_BAR))[i] = 0;
  for (long i = gid; i < 62 * NAD; i += gstr) {
    const int k2 = (int)(i >> 7), ad = (int)(i & 127);
    float acc = 0.f;
    for (int f = 0; f < 32; ++f) acc += p.lconv[k2 * 32 + f] * p.wloc[f * NAD + ad];
    ws[M2_W2 + i] = acc;
  }
  {
    const int b = wg >> 3, s0 = (wg & 7) * 32;
    const int sl = tid & 31, adg = tid >> 5;
    const float* mrow = p.memory + (size_t)(b * NS + s0 + sl) * NE;
    const float* wmb  = p.wm + adg * 16;
    float acc[16];
#pragma unroll
    for (int j = 0; j < 16; ++j) acc[j] = 0.f;
    for (int k = 0; k < NE; ++k) {
      const float mv = mrow[k];
      const float* wr = wmb + (size_t)k * NAD;
#pragma unroll
      for (int j = 0; j < 16; ++j) acc[j] += mv * wr[j];
    }
#pragma unroll
    for (int j = 0; j < 16; ++j)
      u16[M2_K16 + (size_t)(b * NAD + adg * 16 + j) * NS + s0 + sl] = f2bf(acc[j]);
  }
  for (long i = gid; i < (long)NB * KA + (long)NB * KD; i += gstr)
    u16[M2_X16A + i] = 0;
  if constexpr (USEMEM) {
    for (long i = gid; i < (long)NB * NS * NE; i += gstr)
      u16[M2_MEM16 + i] = f2bf(p.memory[i]);
  }
  for (int tile = wg; tile < 3584 + 5120; tile += G) {
    const bool iA = tile < 3584;
    const int tt = iA ? tile : tile - 3584;
    const int NKB = iA ? 56 : 80;
    const int nt4 = tt / NKB, kb = tt % NKB;
    const int kx = iA ? 768 : 1536;
    const int r = tid >> 3, cgp = (tid & 7) * 8;
    const int k = kb * 32 + r;
    const float* src = iA
        ? (k < kx ? p.awx + (size_t)k * ZC : p.awh + (size_t)(k - kx) * ZC)
        : (k < kx ? p.dwx + (size_t)k * ZC : p.dwh + (size_t)(k - kx) * ZC);
    const float* sp = src + nt4 * 64 + cgp;
    const float4 v0 = *(const float4*)sp;
    const float4 v1 = *(const float4*)(sp + 4);
    __syncthreads();
    *(float4*)(sm + r * 64 + cgp)     = v0;
    *(float4*)(sm + r * 64 + cgp + 4) = v1;
    __syncthreads();
    const int blk = tid >> 6, l = tid & 63;
    const int n16 = nt4 * 4 + blk;
    bf16x8 pk;
#pragma unroll
    for (int j = 0; j < 8; ++j)
      pk[j] = (short)f2bf(sm[((l >> 4) * 8 + j) * 64 + blk * 16 + (l & 15)]);
    unsigned short* dst = u16 + (iA ? M2_WAT : M2_WDT)
                        + ((size_t)(n16 * NKB + kb)) * 512 + l * 8;
    *(bf16x8*)dst = pk;
  }
  if (wg >= 320 && wg < 328) do_s1(p, ws + M2_PM1, 0, wg - 320, tid);
}

__device__ void do_fl2(const Params& p, float* sm, int b, int tid) {
  float* ws = p.ws;
  unsigned short* u16 = (unsigned short*)(ws + M2_FEND);
  float* chunk = sm;
  float* wp0 = sm + 4000;
  float* wp1 = sm + 4320;
  for (int i = tid; i < 288; i += 256) { wp0[i] = 0.f; wp1[i] = 0.f; }
  __syncthreads();
  wp0[15 + tid] = ws[M2_WGL + b * NS + tid];
  wp1[15 + tid] = ws[M2_WCU + b * NS + tid];
  __syncthreads();
  float x0[31], x1[31];
#pragma unroll
  for (int k = 0; k < 31; ++k) { x0[k] = wp0[tid + k]; x1[k] = wp1[tid + k]; }
  const unsigned short* kb16 = u16 + M2_K16 + (size_t)(b * NAD) * NS + tid;
  unsigned short* fb16 = u16 + M2_FL16 + (size_t)(b * NAD) * NS + tid;
  const float* W2g = ws + M2_W2;
  for (int ch = 0; ch < 2; ++ch) {
    for (int i = tid; i < 62 * 64; i += 256) {
      const int k2 = i >> 6, adl = i & 63;
      chunk[i] = W2g[k2 * NAD + ch * 64 + adl];
    }
    __syncthreads();
    for (int adl = 0; adl < 64; ++adl) {
      const int ad = ch * 64 + adl;
      float acc = bf2f(kb16[(size_t)ad * NS]);
#pragma unroll
      for (int k = 0; k < 31; ++k)
        acc = fmaf(x0[k], chunk[(2 * k) * 64 + adl],
              fmaf(x1[k], chunk[(2 * k + 1) * 64 + adl], acc));
      fb16[(size_t)ad * NS] = f2bf(acc);
    }
    __syncthreads();
  }
}

__device__ void phase1_2(const Params& p, float* sm, int wg, int tid, int t) {
  float* ws = p.ws;
  unsigned short* u16 = (unsigned short*)(ws + M2_FEND);
  if (wg < 256) {
    const bool isA = wg < 128;
    if ((isA && t < NT) || (!isA && t >= 1)) {
      const int g   = isA ? wg : wg - 128;
      const int kc  = g & 1, nb4 = g >> 1;
      const int NKB = isA ? 56 : 80;
      const int nks = isA ? 28 : 40;
      const int kb0 = kc * nks;
      const int Kp  = isA ? KA : KD;
      const unsigned short* wT  = u16 + (isA ? M2_WAT : M2_WDT);
      const unsigned short* x16 = u16 + (isA ? M2_X16A : M2_X16D);
      float* zout = ws + (isA ? M2_ZAP : M2_ZDP) + (size_t)kc * NB * ZC;
      const int l = tid & 63;
      const int n16 = nb4 * 4 + (tid >> 6);
      const unsigned short* wb = wT + ((size_t)(n16 * NKB + kb0)) * 512 + l * 8;
      const unsigned short* xb = x16 + (size_t)(l & 15) * Kp + kb0 * 32 + (l >> 4) * 8;
      f32x4 acc[4];
#pragma unroll
      for (int m = 0; m < 4; ++m) acc[m] = f32x4{0.f, 0.f, 0.f, 0.f};
#pragma unroll 4
      for (int ks = 0; ks < nks; ++ks) {
        const bf16x8 bfr = *(const bf16x8*)(wb + (size_t)ks * 512);
        const bf16x8 a0 = *(const bf16x8*)(xb + ks * 32);
        const bf16x8 a1 = *(const bf16x8*)(xb + ks * 32 + (size_t)16 * Kp);
        const bf16x8 a2 = *(const bf16x8*)(xb + ks * 32 + (size_t)32 * Kp);
        const bf16x8 a3 = *(const bf16x8*)(xb + ks * 32 + (size_t)48 * Kp);
        acc[0] = __builtin_amdgcn_mfma_f32_16x16x32_bf16(a0, bfr, acc[0], 0, 0, 0);
        acc[1] = __builtin_amdgcn_mfma_f32_16x16x32_bf16(a1, bfr, acc[1], 0, 0, 0);
        acc[2] = __builtin_amdgcn_mfma_f32_16x16x32_bf16(a2, bfr, acc[2], 0, 0, 0);
        acc[3] = __builtin_amdgcn_mfma_f32_16x16x32_bf16(a3, bfr, acc[3], 0, 0, 0);
      }
      const int ncol = n16 * 16 + (l & 15);
      const int rb = (l >> 4) * 4;
#pragma unroll
      for (int mb = 0; mb < 4; ++mb)
#pragma unroll
        for (int r = 0; r < 4; ++r)
          zout[(size_t)(mb * 16 + rb + r) * ZC + ncol] = acc[mb][r];
    }
  } else if (wg < 320) {
    if (t < NT) do_fl2(p, sm, wg - 256, tid);
  } else if (wg < 328) {
    if (t + 1 < NT) do_s1(p, ws + M2_PM1, t + 1, wg - 320, tid);
  }
}

template<bool USEMEM>
__device__ void phase2_2(const Params& p, float* sm, int wg, int tid, int t) {
  float* ws = p.ws;
  unsigned short* u16 = (unsigned short*)(ws + M2_FEND);
  if (wg < 64) {
    if (t < NT) {
      const int b = wg;
      float* h_sh = sm;
      float* q_sh = sm + 1024;
      float* red  = sm + 1152;
      float* w_sh = sm + 1408;
      float* c_a  = ws + M2_CA;
      float* h_a  = ws + M2_HA;
      unsigned short* xA = u16 + M2_X16A + (size_t)b * KA;
      unsigned short* xD = u16 + M2_X16D + (size_t)b * KD;
      const float* za0 = ws + M2_ZAP + (size_t)b * ZC;
      const float* za1 = za0 + (size_t)NB * ZC;
#pragma unroll
      for (int j = 0; j < 4; ++j) {
        const int g = tid + j * 256;
        const float zi = p.ab[g]        + za0[g]        + za1[g];
        const float zf = p.ab[1024 + g] + za0[1024 + g] + za1[1024 + g];
        const float zg = p.ab[2048 + g] + za0[2048 + g] + za1[2048 + g];
        const float zo = p.ab[3072 + g] + za0[3072 + g] + za1[3072 + g];
        const float cold = c_a[b * NA + g];
        const float iv = sigm(zi), fv = sigm(zf), gv = tanh_t(zg), ov = sigm(zo);
        const float c2 = fv * cold + iv * gv;
        const float h2 = ov * tanh_t(c2);
        c_a[b * NA + g] = c2;
        h_a[b * NA + g] = h2;
        h_sh[g] = h2;
        xA[768 + g] = f2bf(h2);
        xD[g]       = f2bf(h2);
      }
      __syncthreads();
      {
        const int ad = tid & 127, kh = tid >> 7;
        float acc = 0.f;
        const float* wqp = p.wq + ad;
#pragma unroll 8
        for (int k = kh * 512; k < kh * 512 + 512; ++k) acc += h_sh[k] * wqp[(size_t)k * NAD];
        red[tid] = acc;
      }
      __syncthreads();
      if (tid < 128) q_sh[tid] = red[tid] + red[tid + 128];
      __syncthreads();
      float ev = 0.f;
      {
        const unsigned short* flp = u16 + M2_FL16 + (size_t)(b * NAD) * NS + tid;
#pragma unroll 8
        for (int ad = 0; ad < NAD; ++ad)
          ev += tanh_t(q_sh[ad] + bf2f(flp[(size_t)ad * NS])) * p.vatt[ad];
      }
      red[tid] = ev; __syncthreads();
      for (int off = 128; off > 0; off >>= 1) {
        if (tid < off) red[tid] = fmaxf(red[tid], red[tid + off]);
        __syncthreads();
      }
      const float mx = red[0];
      __syncthreads();
      const float ex = __expf(ev - mx);
      red[tid] = ex; __syncthreads();
      for (int off = 128; off > 0; off >>= 1) {
        if (tid < off) red[tid] += red[tid + off];
        __syncthreads();
      }
      const float wv = ex / red[0];
      w_sh[tid] = wv;
      ws[M2_WGL + b * NS + tid] = wv;
      ws[M2_WCU + b * NS + tid] += wv;
      p.out[ALIGN_BASE + (size_t)b * NT * NS + (size_t)t * NS + tid] = wv;
      __syncthreads();
      {
        float a0 = 0.f, a1 = 0.f;
        if constexpr (USEMEM) {
          const unsigned short* mb16 = u16 + M2_MEM16 + (size_t)b * NS * NE;
#pragma unroll 8
          for (int ss = 0; ss < NS; ++ss) {
            const float wcur = w_sh[ss];
            a0 += wcur * bf2f(mb16[(size_t)ss * NE + tid]);
            a1 += wcur * bf2f(mb16[(size_t)ss * NE + tid + 256]);
          }
        } else {
          const float* mb = p.memory + (size_t)b * NS * NE;
#pragma unroll 8
          for (int ss = 0; ss < NS; ++ss) {
            const float wcur = w_sh[ss];
            a0 += wcur * mb[(size_t)ss * NE + tid];
            a1 += wcur * mb[(size_t)ss * NE + tid + 256];
          }
        }
        float* cdst = ws + M2_CTX + (t & 1) * (NB * NE) + b * NE;
        cdst[tid] = a0;
        cdst[tid + 256] = a1;
        xA[256 + tid]  = f2bf(a0);
        xA[512 + tid]  = f2bf(a1);
        xD[1024 + tid] = f2bf(a0);
        xD[1280 + tid] = f2bf(a1);
      }
    }
  } else if (wg < 128) {
    if (t >= 1) {
      const int b = wg - 64;
      const int tm1 = t - 1;
      float* h_sh = sm;
      float* red  = sm + 1024;
      float* c_d  = ws + M2_CD;
      float* h_d  = ws + M2_HD;
      unsigned short* xD = u16 + M2_X16D + (size_t)b * KD;
      const float* zd0 = ws + M2_ZDP + (size_t)b * ZC;
      const float* zd1 = zd0 + (size_t)NB * ZC;
#pragma unroll
      for (int j = 0; j < 4; ++j) {
        const int g = tid + j * 256;
        const float zi = p.db[g]        + zd0[g]        + zd1[g];
        const float zf = p.db[1024 + g] + zd0[1024 + g] + zd1[1024 + g];
        const float zg = p.db[2048 + g] + zd0[2048 + g] + zd1[2048 + g];
        const float zo = p.db[3072 + g] + zd0[3072 + g] + zd1[3072 + g];
        const float cold = c_d[b * ND + g];
        const float iv = sigm(zi), fv = sigm(zf), gv = tanh_t(zg), ov = sigm(zo);
        const float c2 = fv * cold + iv * gv;
        const float h2 = ov * tanh_t(c2);
        c_d[b * ND + g] = c2;
        h_d[b * ND + g] = h2;
        h_sh[g] = h2;
        xD[1536 + g] = f2bf(h2);
      }
      __syncthreads();
      const float* ctxp = ws + M2_CTX + (tm1 & 1) * (NB * NE) + b * NE;
      {
        float acc = 0.f;
        for (int k = tid; k < 1536; k += 256) {
          const float v = (k < 1024) ? h_sh[k] : ctxp[k - 1024];
          acc += v * p.gatew[k];
        }
        red[tid] = acc;
      }
      __syncthreads();
      for (int off = 128; off > 0; off >>= 1) {
        if (tid < off) red[tid] += red[tid + off];
        __syncthreads();
      }
      if (tid == 0) p.out[STOP_BASE + (size_t)b * NT + tm1] = sigm(red[0] + p.gateb[0]);
      __syncthreads();
      if (tid < 240) {
        const int m = tid % 80, kh = tid / 80;
        float acc = 0.f;
#pragma unroll 4
        for (int k = kh * 512; k < kh * 512 + 512; ++k) {
          const float v = (k < 1024) ? h_sh[k] : ctxp[k - 1024];
          acc += v * p.projw[(size_t)k * 80 + m];
        }
        red[kh * 80 + m] = acc;
      }
      __syncthreads();
      if (tid < 80) {
        const float mval = p.projb[tid] + red[tid] + red[80 + tid] + red[160 + tid];
        p.out[MEL_BASE + (size_t)b * NT * NMEL + (size_t)tm1 * NMEL + tid] = mval;
      }
    }
  } else if (wg < 144) {
    if (t + 1 < NT)
      do_s2<2>(p, ws + M2_PM1, nullptr, u16 + M2_X16A, wg - 128, tid);
  }
}

template<bool USEMEM>
__global__ __launch_bounds__(256, 2) void taco2(Params p) {
  cg::grid_group grid = cg::this_grid();
  const int wg  = blockIdx.x;
  const int tid = threadIdx.x;
  __shared__ float sm[SMN];

  pre_a2<USEMEM>(p, sm, wg, tid);
  grid.sync();
  if (wg >= 128 && wg < 144)
    do_s2<2>(p, p.ws + M2_PM1, nullptr,
             (unsigned short*)(p.ws + M2_FEND) + M2_X16A, wg - 128, tid);
  grid.sync();
  unsigned* bar = (unsigned*)(p.ws + M2_BAR);
  for (int t = 0; t <= NT; ++t) {
    phase1_2(p, sm, wg, tid, t);
    gbar(bar, wg, tid);
    phase2_2<USEMEM>(p, sm, wg, tid, t);
    gbar(bar, wg, tid);
  }
}

// ================= legacy MODE 0/1 =================
template<int MODE>
__device__ void pre_a(const Params& p, int wg, int tid) {
  float* ws = p.ws;
  const int gid = wg * 256 + tid;
  for (int i = gid; i < ZERO_CNT; i += G * 256) (ws + OFF_HA)[i] = 0.f;
  if constexpr (MODE == 0) {
    for (int i = gid; i < NB * ZC; i += G * 256) {
      ws[OFF_ZA + i] = p.ab[i & (ZC - 1)];
      ws[OFF_ZD + i] = p.db[i & (ZC - 1)];
    }
  }
  for (int i = gid; i < 62 * NAD; i += G * 256) {
    const int k2 = i >> 7, ad = i & 127;
    float acc = 0.f;
    for (int f = 0; f < 32; ++f) acc += p.lconv[k2 * 32 + f] * p.wloc[f * NAD + ad];
    ws[OFF_W2 + i] = acc;
  }
  {
    const int b = wg >> 3, s0 = (wg & 7) * 32;
    const int sl = tid & 31, adg = tid >> 5;
    const float* mrow = p.memory + (size_t)(b * NS + s0 + sl) * NE;
    const float* wmb  = p.wm + adg * 16;
    float acc[16];
#pragma unroll
    for (int j = 0; j < 16; ++j) acc[j] = 0.f;
    for (int k = 0; k < NE; ++k) {
      const float mv = mrow[k];
      const float* wr = wmb + (size_t)k * NAD;
#pragma unroll
      for (int j = 0; j < 16; ++j) acc[j] += mv * wr[j];
    }
#pragma unroll
    for (int j = 0; j < 16; ++j)
      ws[OFF_KEYST + (b * NAD + adg * 16 + j) * NS + s0 + sl] = acc[j];
  }
  if (wg >= 496 && wg < 504) do_s1(p, ws + OFF_PM1, 0, wg - 496, tid);
}

__device__ void do_fl(const Params& p, float* sm, int b, int tid) {
  float* ws = p.ws;
  float* chunk = sm;
  float* wp0 = sm + 4000;
  float* wp1 = sm + 4320;
  for (int i = tid; i < 288; i += 256) { wp0[i] = 0.f; wp1[i] = 0.f; }
  __syncthreads();
  wp0[15 + tid] = ws[OFF_WGL + b * NS + tid];
  wp1[15 + tid] = ws[OFF_WCU + b * NS + tid];
  __syncthreads();
  float x0[31], x1[31];
#pragma unroll
  for (int k = 0; k < 31; ++k) { x0[k] = wp0[tid + k]; x1[k] = wp1[tid + k]; }
  const float* kb = ws + OFF_KEYST + (b * NAD) * NS + tid;
  float* fb = ws + OFF_FL + (b * NAD) * NS + tid;
  const float* W2g = ws + OFF_W2;
  for (int ch = 0; ch < 2; ++ch) {
    for (int i = tid; i < 62 * 64; i += 256) {
      const int k2 = i >> 6, adl = i & 63;
      chunk[i] = W2g[k2 * NAD + ch * 64 + adl];
    }
    __syncthreads();
    for (int adl = 0; adl < 64; ++adl) {
      const int ad = ch * 64 + adl;
      float acc = kb[ad * NS];
#pragma unroll
      for (int k = 0; k < 31; ++k)
        acc = fmaf(x0[k], chunk[(2 * k) * 64 + adl],
              fmaf(x1[k], chunk[(2 * k + 1) * 64 + adl], acc));
      fb[ad * NS] = acc;
    }
    __syncthreads();
  }
}

template<int MODE>
__device__ void phase1(const Params& p, float* sm, int wg, int tid, int t) {
  float* ws = p.ws;
  if (wg < 176) {
    if (t < NT) {
      const int cb = wg & 7, bs = (wg >> 3) & 1, kci = wg >> 4;
      const int col0 = cb * 512, b0 = bs * 32, k0 = kci * 163;
      const int kc = min(163, KA - k0);
      const float* pcur = ws + OFF_P + (t & 1) * (NB * NP);
      const float* ctxp = ws + OFF_CTX + ((t + 1) & 1) * (NB * NE);
      const float* h_a  = ws + OFF_HA;
      for (int bb = 0; bb < 32; ++bb) {
        const int b = b0 + bb;
        for (int kk = tid; kk < kc; kk += 256) {
          const int k = k0 + kk;
          float v;
          if (k < NP)           v = pcur[b * NP + k];
          else if (k < NP + NE) v = ctxp[b * NE + (k - NP)];
          else                  v = h_a[b * NA + (k - NP - NE)];
          sm[bb * 164 + kk] = v;
        }
      }
      __syncthreads();
      const int bgrp = tid >> 6, cgrp = tid & 63;
      const int c = col0 + cgrp * 8;
      float acc[8][8];
#pragma unroll
      for (int i = 0; i < 8; ++i)
#pragma unroll
        for (int j = 0; j < 8; ++j) acc[i][j] = 0.f;
      const float* sxb = sm + bgrp * 8 * 164;
#pragma unroll 2
      for (int kk = 0; kk < kc; ++kk) {
        const int k = k0 + kk;
        const float* wr = (k < 768) ? (p.awx + (size_t)k * ZC + c)
                                    : (p.awh + (size_t)(k - 768) * ZC + c);
        const float4 w0 = *(const float4*)wr;
        const float4 w1 = *(const float4*)(wr + 4);
#pragma unroll
        for (int i = 0; i < 8; ++i) {
          const float x = sxb[i * 164 + kk];
          acc[i][0] += x * w0.x; acc[i][1] += x * w0.y;
          acc[i][2] += x * w0.z; acc[i][3] += x * w0.w;
          acc[i][4] += x * w1.x; acc[i][5] += x * w1.y;
          acc[i][6] += x * w1.z; acc[i][7] += x * w1.w;
        }
      }
      if constexpr (MODE == 1) {
        float* zap = ws + OFF_ZAP;
#pragma unroll
        for (int i = 0; i < 8; ++i) {
          const int b = b0 + bgrp * 8 + i;
          float* dst = zap + (size_t)(kci * NB + b) * ZC + c;
          *(float4*)dst       = make_float4(acc[i][0], acc[i][1], acc[i][2], acc[i][3]);
          *(float4*)(dst + 4) = make_float4(acc[i][4], acc[i][5], acc[i][6], acc[i][7]);
        }
      } else {
        float* z_a = ws + OFF_ZA;
#pragma unroll
        for (int i = 0; i < 8; ++i) {
          const int b = b0 + bgrp * 8 + i;
#pragma unroll
          for (int j = 0; j < 8; ++j) atomicAdd(&z_a[b * ZC + c + j], acc[i][j]);
        }
      }
      __syncthreads();
    }
  } else if (wg < 432) {
    if (t >= 1) {
      const int lw = wg - 176;
      const int cb = lw & 7, bs = (lw >> 3) & 1, kci = lw >> 4;
      const int col0 = cb * 512, b0 = bs * 32, k0 = kci * 160;
      const int kc = 160;
      const float* ctxp = ws + OFF_CTX + ((t + 1) & 1) * (NB * NE);
      const float* h_a  = ws + OFF_HA;
      const float* h_d  = ws + OFF_HD;
      for (int bb = 0; bb < 32; ++bb) {
        const int b = b0 + bb;
        for (int kk = tid; kk < kc; kk += 256) {
          const int k = k0 + kk;
          float v;
          if (k < NA)           v = h_a[b * NA + k];
          else if (k < NA + NE) v = ctxp[b * NE + (k - NA)];
          else                  v = h_d[b * ND + (k - NA - NE)];
          sm[bb * 161 + kk] = v;
        }
      }
      __syncthreads();
      const int bgrp = tid >> 6, cgrp = tid & 63;
      const int c = col0 + cgrp * 8;
      float acc[8][8];
#pragma unroll
      for (int i = 0; i < 8; ++i)
#pragma unroll
        for (int j = 0; j < 8; ++j) acc[i][j] = 0.f;
      const float* sxb = sm + bgrp * 8 * 161;
#pragma unroll 2
      for (int kk = 0; kk < kc; ++kk) {
        const int k = k0 + kk;
        const float* wr = (k < 1536) ? (p.dwx + (size_t)k * ZC + c)
                                     : (p.dwh + (size_t)(k - 1536) * ZC + c);
        const float4 w0 = *(const float4*)wr;
        const float4 w1 = *(const float4*)(wr + 4);
#pragma unroll
        for (int i = 0; i < 8; ++i) {
          const float x = sxb[i * 161 + kk];
          acc[i][0] += x * w0.x; acc[i][1] += x * w0.y;
          acc[i][2] += x * w0.z; acc[i][3] += x * w0.w;
          acc[i][4] += x * w1.x; acc[i][5] += x * w1.y;
          acc[i][6] += x * w1.z; acc[i][7] += x * w1.w;
        }
      }
      if constexpr (MODE == 1) {
        float* zdp = ws + OFF_ZDP;
#pragma unroll
        for (int i = 0; i < 8; ++i) {
          const int b = b0 + bgrp * 8 + i;
          float* dst = zdp + (size_t)(kci * NB + b) * ZC + c;
          *(float4*)dst       = make_float4(acc[i][0], acc[i][1], acc[i][2], acc[i][3]);
          *(float4*)(dst + 4) = make_float4(acc[i][4], acc[i][5], acc[i][6], acc[i][7]);
        }
      } else {
        float* z_d = ws + OFF_ZD;
#pragma unroll
        for (int i = 0; i < 8; ++i) {
          const int b = b0 + bgrp * 8 + i;
#pragma unroll
          for (int j = 0; j < 8; ++j) atomicAdd(&z_d[b * ZC + c + j], acc[i][j]);
        }
      }
      __syncthreads();
    }
  } else if (wg < 496) {
    if (t < NT) do_fl(p, sm, wg - 432, tid);
  } else if (wg < 504) {
    if (t + 1 < NT) do_s1(p, ws + OFF_PM1, t + 1, wg - 496, tid);
  }
}

template<int MODE>
__device__ void phase2(const Params& p, float* sm, int wg, int tid, int t) {
  float* ws = p.ws;
  if (wg < 64) {
    if (t < NT) {
      const int b = wg;
      float* h_sh = sm;
      float* q_sh = sm + 1024;
      float* red  = sm + 1152;
      float* w_sh = sm + 1408;
      float* c_a  = ws + OFF_CA;
      float* h_a  = ws + OFF_HA;
#pragma unroll
      for (int j = 0; j < 4; ++j) {
        const int g = tid + j * 256;
        float zi, zf, zg, zo;
        if constexpr (MODE == 1) {
          zi = p.ab[g]; zf = p.ab[1024 + g]; zg = p.ab[2048 + g]; zo = p.ab[3072 + g];
          const float* zap = ws + OFF_ZAP + (size_t)b * ZC;
#pragma unroll 1
          for (int kci = 0; kci < NKA; ++kci) {
            const float* zp = zap + (size_t)kci * NB * ZC;
            zi += zp[g]; zf += zp[1024 + g]; zg += zp[2048 + g]; zo += zp[3072 + g];
          }
        } else {
          float* z_a = ws + OFF_ZA;
          zi = z_a[b * ZC + g];
          zf = z_a[b * ZC + 1024 + g];
          zg = z_a[b * ZC + 2048 + g];
          zo = z_a[b * ZC + 3072 + g];
          z_a[b * ZC + g]        = p.ab[g];
          z_a[b * ZC + 1024 + g] = p.ab[1024 + g];
          z_a[b * ZC + 2048 + g] = p.ab[2048 + g];
          z_a[b * ZC + 3072 + g] = p.ab[3072 + g];
        }
        const float cold = c_a[b * NA + g];
        const float iv = sigm(zi), fv = sigm(zf), gv = tanh_t(zg), ov = sigm(zo);
        const float c2 = fv * cold + iv * gv;
        const float h2 = ov * tanh_t(c2);
        c_a[b * NA + g] = c2;
        h_a[b * NA + g] = h2;
        h_sh[g] = h2;
      }
      __syncthreads();
      {
        const int ad = tid & 127, kh = tid >> 7;
        float acc = 0.f;
        const float* wqp = p.wq + ad;
        for (int k = kh * 512; k < kh * 512 + 512; ++k) acc += h_sh[k] * wqp[(size_t)k * NAD];
        red[tid] = acc;
      }
      __syncthreads();
      if (tid < 128) q_sh[tid] = red[tid] + red[tid + 128];
      __syncthreads();
      float ev = 0.f;
      {
        const float* flp = ws + OFF_FL + (b * NAD) * NS + tid;
        for (int ad = 0; ad < NAD; ++ad)
          ev += tanh_t(q_sh[ad] + flp[ad * NS]) * p.vatt[ad];
      }
      red[tid] = ev; __syncthreads();
      for (int off = 128; off > 0; off >>= 1) {
        if (tid < off) red[tid] = fmaxf(red[tid], red[tid + off]);
        __syncthreads();
      }
      const float mx = red[0];
      __syncthreads();
      const float ex = __expf(ev - mx);
      red[tid] = ex; __syncthreads();
      for (int off = 128; off > 0; off >>= 1) {
        if (tid < off) red[tid] += red[tid + off];
        __syncthreads();
      }
      const float wv = ex / red[0];
      w_sh[tid] = wv;
      ws[OFF_WGL + b * NS + tid] = wv;
      ws[OFF_WCU + b * NS + tid] += wv;
      p.out[ALIGN_BASE + (size_t)b * NT * NS + (size_t)t * NS + tid] = wv;
      __syncthreads();
      {
        float a0 = 0.f, a1 = 0.f;
        const float* mb = p.memory + (size_t)b * NS * NE;
        for (int ss = 0; ss < NS; ++ss) {
          const float wcur = w_sh[ss];
          a0 += wcur * mb[ss * NE + tid];
          a1 += wcur * mb[ss * NE + tid + 256];
        }
        float* cdst = ws + OFF_CTX + (t & 1) * (NB * NE) + b * NE;
        cdst[tid] = a0;
        cdst[tid + 256] = a1;
      }
    }
  } else if (wg < 128) {
    if (t >= 1) {
      const int b = wg - 64;
      const int tm1 = t - 1;
      float* h_sh = sm;
      float* red  = sm + 1024;
      float* c_d  = ws + OFF_CD;
      float* h_d  = ws + OFF_HD;
#pragma unroll
      for (int j = 0; j < 4; ++j) {
        const int g = tid + j * 256;
        float zi, zf, zg, zo;
        if constexpr (MODE == 1) {
          zi = p.db[g]; zf = p.db[1024 + g]; zg = p.db[2048 + g]; zo = p.db[3072 + g];
          const float* zdp = ws + OFF_ZDP + (size_t)b * ZC;
#pragma unroll 1
          for (int kci = 0; kci < NKD; ++kci) {
            const float* zp = zdp + (size_t)kci * NB * ZC;
            zi += zp[g]; zf += zp[1024 + g]; zg += zp[2048 + g]; zo += zp[3072 + g];
          }
        } else {
          float* z_d = ws + OFF_ZD;
          zi = z_d[b * ZC + g];
          zf = z_d[b * ZC + 1024 + g];
          zg = z_d[b * ZC + 2048 + g];
          zo = z_d[b * ZC + 3072 + g];
          z_d[b * ZC + g]        = p.db[g];
          z_d[b * ZC + 1024 + g] = p.db[1024 + g];
          z_d[b * ZC + 2048 + g] = p.db[2048 + g];
          z_d[b * ZC + 3072 + g] = p.db[3072 + g];
        }
        const float cold = c_d[b * ND + g];
        const float iv = sigm(zi), fv = sigm(zf), gv = tanh_t(zg), ov = sigm(zo);
        const float c2 = fv * cold + iv * gv;
        const float h2 = ov * tanh_t(c2);
        c_d[b * ND + g] = c2;
        h_d[b * ND + g] = h2;
        h_sh[g] = h2;
      }
      __syncthreads();
      const float* ctxp = ws + OFF_CTX + (tm1 & 1) * (NB * NE) + b * NE;
      {
        float acc = 0.f;
        for (int k = tid; k < 1536; k += 256) {
          const float v = (k < 1024) ? h_sh[k] : ctxp[k - 1024];
          acc += v * p.gatew[k];
        }
        red[tid] = acc;
      }
      __syncthreads();
      for (int off = 128; off > 0; off >>= 1) {
        if (tid < off) red[tid] += red[tid + off];
        __syncthreads();
      }
      if (tid == 0) p.out[STOP_BASE + (size_t)b * NT + tm1] = sigm(red[0] + p.gateb[0]);
      __syncthreads();
      if (tid < 240) {
        const int m = tid % 80, kh = tid / 80;
        float acc = 0.f;
        for (int k = kh * 512; k < kh * 512 + 512; ++k) {
          const float v = (k < 1024) ? h_sh[k] : ctxp[k - 1024];
          acc += v * p.projw[(size_t)k * 80 + m];
        }
        red[kh * 80 + m] = acc;
      }
      __syncthreads();
      if (tid < 80) {
        const float mval = p.projb[tid] + red[tid] + red[80 + tid] + red[160 + tid];
        p.out[MEL_BASE + (size_t)b * NT * NMEL + (size_t)tm1 * NMEL + tid] = mval;
      }
    }
  } else if (wg < 144) {
    if (t + 1 < NT)
      do_s2<MODE>(p, ws + OFF_PM1, ws + OFF_P + ((t + 1) & 1) * (NB * NP),
                  nullptr, wg - 128, tid);
  }
}

template<int MODE>
__global__ __launch_bounds__(256, 2) void taco_coop(Params p) {
  cg::grid_group grid = cg::this_grid();
  const int wg  = blockIdx.x;
  const int tid = threadIdx.x;
  __shared__ float sm[SMN];
  pre_a<MODE>(p, wg, tid);
  grid.sync();
  if (wg >= 128 && wg < 144)
    do_s2<MODE>(p, p.ws + OFF_PM1, p.ws + OFF_P, nullptr, wg - 128, tid);
  grid.sync();
  for (int t = 0; t <= NT; ++t) {
    phase1<MODE>(p, sm, wg, tid, t);
    grid.sync();
    phase2<MODE>(p, sm, wg, tid, t);
    grid.sync();
  }
}

__global__ __launch_bounds__(256, 2) void k_pre_a(Params p) { pre_a<0>(p, blockIdx.x, threadIdx.x); }
__global__ __launch_bounds__(256, 2) void k_pre_b(Params p) {
  if (blockIdx.x >= 128 && blockIdx.x < 144)
    do_s2<0>(p, p.ws + OFF_PM1, p.ws + OFF_P, nullptr, blockIdx.x - 128, threadIdx.x);
}
__global__ __launch_bounds__(256, 2) void k_p1(Params p, int t) {
  __shared__ float sm[SMN];
  phase1<0>(p, sm, blockIdx.x, threadIdx.x, t);
}
__global__ __launch_bounds__(256, 2) void k_p2(Params p, int t) {
  __shared__ float sm[SMN];
  phase2<0>(p, sm, blockIdx.x, threadIdx.x, t);
}

extern "C" void kernel_launch(void* const* d_in, const int* in_sizes, int n_in,
                              void* d_out, int out_size, void* d_ws, size_t ws_size,
                              hipStream_t stream) {
  (void)in_sizes; (void)n_in; (void)out_size;
  Params prm;
  prm.memory = (const float*)d_in[0];
  prm.mel    = (const float*)d_in[1];
  prm.pw1    = (const float*)d_in[2];
  prm.pw2    = (const float*)d_in[3];
  prm.awx    = (const float*)d_in[4];
  prm.awh    = (const float*)d_in[5];
  prm.ab     = (const float*)d_in[6];
  prm.wq     = (const float*)d_in[7];
  prm.wm     = (const float*)d_in[8];
  prm.lconv  = (const float*)d_in[9];
  prm.wloc   = (const float*)d_in[10];
  prm.vatt   = (const float*)d_in[11];
  prm.dwx    = (const float*)d_in[12];
  prm.dwh    = (const float*)d_in[13];
  prm.db     = (const float*)d_in[14];
  prm.projw  = (const float*)d_in[15];
  prm.projb  = (const float*)d_in[16];
  prm.gatew  = (const float*)d_in[17];
  prm.gateb  = (const float*)d_in[18];
  prm.out = (float*)d_out;
  prm.ws  = (float*)d_ws;

  void* args[] = { &prm };
  hipError_t err = hipErrorUnknown;
  if (ws_size >= (size_t)M3_BYTES) {
    (void)hipFuncSetAttribute((const void*)taco3,
                              hipFuncAttributeMaxDynamicSharedMemorySize, DYN_LDS);
    err = hipLaunchCooperativeKernel((void*)taco3, dim3(G3), dim3(T3),
                                     args, DYN_LDS, stream);
  }
  if (err != hipSuccess && ws_size >= (size_t)M2_BYTES)
    err = hipLaunchCooperativeKernel((void*)taco2<true>, dim3(G), dim3(256), args, 0, stream);
  if (err != hipSuccess && ws_size >= (size_t)M2_BYTES_NM)
    err = hipLaunchCooperativeKernel((void*)taco2<false>, dim3(G), dim3(256), args, 0, stream);
  if (err != hipSuccess && ws_size >= (size_t)WS_FULL * sizeof(float))
    err = hipLaunchCooperativeKernel((void*)taco_coop<1>, dim3(G), dim3(256), args, 0, stream);
  if (err != hipSuccess)
    err = hipLaunchCooperativeKernel((void*)taco_coop<0>, dim3(G), dim3(256), args, 0, stream);
  if (err != hipSuccess) {
    k_pre_a<<<dim3(G), dim3(256), 0, stream>>>(prm);
    k_pre_b<<<dim3(G), dim3(256), 0, stream>>>(prm);
    for (int t = 0; t <= NT; ++t) {
      k_p1<<<dim3(G), dim3(256), 0, stream>>>(prm, t);
      k_p2<<<dim3(G), dim3(256), 0, stream>>>(prm, t);
    }
  }
}